// Round 20
// baseline (103.962 us; speedup 1.0000x reference)
//
#include <hip/hip_runtime.h>
#include <hip/hip_bf16.h>
#include <math.h>

#define S_LEN 4096
#define DMODEL 2048
#define HEADD 128

typedef __attribute__((ext_vector_type(8))) short short8;
typedef __attribute__((ext_vector_type(4))) float floatx4;

__device__ __forceinline__ short f2bs(float f) {
  __hip_bfloat16 h = __float2bfloat16(f);
  short s; __builtin_memcpy(&s, &h, 2); return s;
}
__device__ __forceinline__ float bs2f(short s) {
  unsigned u = ((unsigned)(unsigned short)s) << 16;
  float f; __builtin_memcpy(&f, &u, 4); return f;
}
__device__ __forceinline__ int pkbf(float a, float b) {  // (lo=a, hi=b) bf16 pair
  return (int)(((unsigned)(unsigned short)f2bs(b) << 16) |
               (unsigned)(unsigned short)f2bs(a));
}

// ---- Kernel 1: convert Wq,Wk,Wv (fp32 [128][2048] each) -> wc bf16 [384][2048]
__global__ __launch_bounds__(256) void convw_kernel(const float* __restrict__ wq,
                                                    const float* __restrict__ wk,
                                                    const float* __restrict__ wv,
                                                    short* __restrict__ wc) {
  const int per = 128 * 2048;
  int e = (blockIdx.x * blockDim.x + threadIdx.x) * 4;
  const float* src = (e < per) ? wq : (e < 2 * per) ? wk : wv;
  int off = e & (per - 1);
  float4 v = *(const float4*)(src + off);
  short4 r;
  r.x = f2bs(v.x); r.y = f2bs(v.y); r.z = f2bs(v.z); r.w = f2bs(v.w);
  *(short4*)(wc + e) = r;
}

// ---- Kernel 2: projection GEMM (unchanged from R19: 64x96 tile, BK=64,
// 12 MFMAs/wave-iter, 32 iters, XOR-swizzled 40KB LDS dbuf)
__global__ __launch_bounds__(256, 3) void proj_kernel(const float* __restrict__ x,
                                                      const short* __restrict__ wc,
                                                      short* __restrict__ qm,
                                                      short* __restrict__ kb,
                                                      short* __restrict__ vstage) {
  const int tid = threadIdx.x;
  const int w = tid >> 6;
  const int lane = tid & 63;
  const int lo = lane & 15, g = lane >> 4;
  const int id = blockIdx.x;
  const int nq = id >> 7, mb = id & 127;
  const int m0 = mb * 64;
  const int n0 = nq * 96;

  __shared__ short xt[2][64 * 64];
  __shared__ short wt[2][96 * 64];

  const int r8 = tid >> 3, sc = tid & 7;
  const float* xs0 = x + (size_t)(m0 + r8) * DMODEL + sc * 8;
  const float* xs1 = x + (size_t)(m0 + 32 + r8) * DMODEL + sc * 8;
  const short* ws0 = wc + (size_t)(n0 + r8) * DMODEL + sc * 8;
  const short* ws1 = wc + (size_t)(n0 + 32 + r8) * DMODEL + sc * 8;
  const short* ws2 = wc + (size_t)(n0 + 64 + r8) * DMODEL + sc * 8;
  const int xl0 = r8 * 64 + ((sc ^ (r8 & 7)) * 8);
  const int xl1 = (32 + r8) * 64 + ((sc ^ (r8 & 7)) * 8);
  const int wlo0 = r8 * 64 + ((sc ^ (r8 & 7)) * 8);
  const int wlo1 = (32 + r8) * 64 + ((sc ^ (r8 & 7)) * 8);
  const int wlo2 = (64 + r8) * 64 + ((sc ^ (r8 & 7)) * 8);

  const int mrow = (w >> 1) * 32;
  const int ncol = (w & 1) * 48;
  int aoff[2][2], boff[3][2];
#pragma unroll
  for (int mi = 0; mi < 2; ++mi) {
    int r = mrow + mi * 16 + lo;
#pragma unroll
    for (int kc = 0; kc < 2; ++kc)
      aoff[mi][kc] = r * 64 + (((kc * 4 + g) ^ (r & 7)) * 8);
  }
#pragma unroll
  for (int t = 0; t < 3; ++t) {
    int r = ncol + t * 16 + lo;
#pragma unroll
    for (int kc = 0; kc < 2; ++kc)
      boff[t][kc] = r * 64 + (((kc * 4 + g) ^ (r & 7)) * 8);
  }

  floatx4 acc[2][3];
#pragma unroll
  for (int mi = 0; mi < 2; ++mi)
#pragma unroll
    for (int t = 0; t < 3; ++t) acc[mi][t] = floatx4{0.f, 0.f, 0.f, 0.f};

  {
    float4 a0 = *(const float4*)(xs0), a1 = *(const float4*)(xs0 + 4);
    float4 b0 = *(const float4*)(xs1), b1 = *(const float4*)(xs1 + 4);
    int4 w0 = *(const int4*)(ws0);
    int4 w1 = *(const int4*)(ws1);
    int4 w2 = *(const int4*)(ws2);
    short8 sA, sB;
    sA[0]=f2bs(a0.x); sA[1]=f2bs(a0.y); sA[2]=f2bs(a0.z); sA[3]=f2bs(a0.w);
    sA[4]=f2bs(a1.x); sA[5]=f2bs(a1.y); sA[6]=f2bs(a1.z); sA[7]=f2bs(a1.w);
    sB[0]=f2bs(b0.x); sB[1]=f2bs(b0.y); sB[2]=f2bs(b0.z); sB[3]=f2bs(b0.w);
    sB[4]=f2bs(b1.x); sB[5]=f2bs(b1.y); sB[6]=f2bs(b1.z); sB[7]=f2bs(b1.w);
    *(short8*)&xt[0][xl0] = sA;
    *(short8*)&xt[0][xl1] = sB;
    *(int4*)&wt[0][wlo0] = w0;
    *(int4*)&wt[0][wlo1] = w1;
    *(int4*)&wt[0][wlo2] = w2;
  }
  __syncthreads();

  int cur = 0;
#pragma unroll 1
  for (int it = 0; it < 32; ++it) {
    float4 a0, a1, b0, b1;
    int4 w0, w1, w2;
    if (it + 1 < 32) {
      const int k = (it + 1) * 64;
      a0 = *(const float4*)(xs0 + k); a1 = *(const float4*)(xs0 + k + 4);
      b0 = *(const float4*)(xs1 + k); b1 = *(const float4*)(xs1 + k + 4);
      w0 = *(const int4*)(ws0 + k);
      w1 = *(const int4*)(ws1 + k);
      w2 = *(const int4*)(ws2 + k);
    }

    {
      const short* xb = &xt[cur][0];
      const short* wb = &wt[cur][0];
      short8 af[2][2], bf[3][2];
#pragma unroll
      for (int mi = 0; mi < 2; ++mi)
#pragma unroll
        for (int kc = 0; kc < 2; ++kc) af[mi][kc] = *(const short8*)(xb + aoff[mi][kc]);
#pragma unroll
      for (int t = 0; t < 3; ++t)
#pragma unroll
        for (int kc = 0; kc < 2; ++kc) bf[t][kc] = *(const short8*)(wb + boff[t][kc]);
#pragma unroll
      for (int kc = 0; kc < 2; ++kc)
#pragma unroll
        for (int mi = 0; mi < 2; ++mi)
#pragma unroll
          for (int t = 0; t < 3; ++t)
            acc[mi][t] = __builtin_amdgcn_mfma_f32_16x16x32_bf16(af[mi][kc], bf[t][kc], acc[mi][t], 0, 0, 0);
    }

    if (it + 1 < 32) {
      short8 sA, sB;
      sA[0]=f2bs(a0.x); sA[1]=f2bs(a0.y); sA[2]=f2bs(a0.z); sA[3]=f2bs(a0.w);
      sA[4]=f2bs(a1.x); sA[5]=f2bs(a1.y); sA[6]=f2bs(a1.z); sA[7]=f2bs(a1.w);
      sB[0]=f2bs(b0.x); sB[1]=f2bs(b0.y); sB[2]=f2bs(b0.z); sB[3]=f2bs(b0.w);
      sB[4]=f2bs(b1.x); sB[5]=f2bs(b1.y); sB[6]=f2bs(b1.z); sB[7]=f2bs(b1.w);
      *(short8*)&xt[cur ^ 1][xl0] = sA;
      *(short8*)&xt[cur ^ 1][xl1] = sB;
      *(int4*)&wt[cur ^ 1][wlo0] = w0;
      *(int4*)&wt[cur ^ 1][wlo1] = w1;
      *(int4*)&wt[cur ^ 1][wlo2] = w2;
    }
    __syncthreads();
    cur ^= 1;
  }

#pragma unroll
  for (int t = 0; t < 3; ++t) {
    int n = n0 + ncol + t * 16 + lo;
#pragma unroll
    for (int mi = 0; mi < 2; ++mi)
#pragma unroll
      for (int j = 0; j < 4; ++j) {
        int m = m0 + mrow + mi * 16 + g * 4 + j;
        float v = acc[mi][t][j];
        if (n < HEADD) {
          qm[(size_t)m * HEADD + n] = f2bs(v * 0.125f);
        } else if (n < 2 * HEADD) {
          kb[(size_t)m * HEADD + (n - HEADD)] = f2bs(v);
        } else {
          vstage[(size_t)m * HEADD + (n - 2 * HEADD)] = f2bs(v);
        }
      }
  }
}

// ---- Kernel 2c: vstage[8192][128] -> vt[b][h][s] via LDS transpose
__global__ __launch_bounds__(256) void conv_v_kernel(const short* __restrict__ vstage,
                                                     short* __restrict__ vt) {
  const int tid = threadIdx.x;
  const int bb = blockIdx.x >> 6, st = blockIdx.x & 63;
  const int s0 = st * 64;

  __shared__ short ld[64][136];

  const int r = tid >> 2, c8 = (tid & 3) * 32;
#pragma unroll
  for (int q = 0; q < 4; ++q) {
    const size_t off = (size_t)(bb * 4096 + s0 + r) * 128 + c8 + q * 8;
    *(short8*)(&ld[r][c8 + q * 8]) = *(const short8*)(vstage + off);
  }
  __syncthreads();

  const int h = tid >> 1, sh = (tid & 1) * 32;
#pragma unroll
  for (int q = 0; q < 4; ++q) {
    short8 t;
#pragma unroll
    for (int i = 0; i < 8; ++i) t[i] = ld[sh + q * 8 + i][h];
    *(short8*)(vt + ((size_t)bb * 128 + h) * 4096 + s0 + sh + q * 8) = t;
  }
}

// ---- Kernel 3: LDS-staged flash attention, 512 thr / 128 q-rows per block.
// grid 512 = 64 qblk x 8 ksp -> EXACTLY 2 blocks/CU = 16 waves/CU (2x R19's
// resident waves; occupancy was the binder, loop unchanged). 8 waves =
// (qsp 0..3) x (stream 0|1) share each K/V tile; staging = exactly one 16B
// chunk per thread for K and V. Zero atomics.
__global__ __launch_bounds__(512, 2) void attn_kernel(const short* __restrict__ qm,
                                                      const short* __restrict__ kb,
                                                      const short* __restrict__ vt,
                                                      short* __restrict__ po,
                                                      float* __restrict__ pls) {
  const int tid = threadIdx.x;
  const int w = tid >> 6;
  const int lane = tid & 63;
  const int lo = lane & 15, g = lane >> 4;
  const int qsp = w >> 1;           // q-subtile pair 0..3
  const int s = w & 1;              // attn stream
  const int id = blockIdx.x;
  const int ksp = id & 7;           // kv eighth -> XCD pin
  const int qblk = id >> 3;         // 0..63 (128 rows each); b = qblk>>5
  const int b = qblk >> 5;
  const int kv_base = ksp * 512;

  __shared__ short kt[2][32 * 128];   // K tile, XOR-swizzled chunks
  __shared__ short vl[2][128 * 32];   // V^T tile, XOR-swizzled chunks

  // staging: one 16B chunk per thread for each of K and V
  const int kr = tid >> 4, kck = tid & 15;    // K row 0..31, chunk 0..15
  const int vr = tid >> 2, vck = tid & 3;     // V row 0..127, chunk 0..3
  const short* kS = kb + (size_t)b * S_LEN * HEADD;
  const short* vS = vt + (size_t)b * HEADD * S_LEN;
  const int kld = kr * 128 + ((kck ^ (kr & 7)) * 8);
  const int vld = vr * 32 + ((vck ^ (vr & 3)) * 8);

  const int rowqA = qblk * 128 + qsp * 32;
  const int rowqB = rowqA + 16;
  const short* qrowA = qm + (size_t)(rowqA + lo) * HEADD + s * 64;
  const short* qrowB = qm + (size_t)(rowqB + lo) * HEADD + s * 64;
  const short8 qA0 = *(const short8*)(qrowA + g * 8);
  const short8 qA1 = *(const short8*)(qrowA + 32 + g * 8);
  const short8 qB0 = *(const short8*)(qrowB + g * 8);
  const short8 qB1 = *(const short8*)(qrowB + 32 + g * 8);

  floatx4 accA[8], accB[8];
#pragma unroll
  for (int n = 0; n < 8; ++n) {
    accA[n] = floatx4{0.f, 0.f, 0.f, 0.f};
    accB[n] = floatx4{0.f, 0.f, 0.f, 0.f};
  }
  float lxA = 0.f, lxB = 0.f;

  const int kc0 = ((s * 8 + g) ^ (lo & 7)) * 8;
  const int kc1 = ((s * 8 + 4 + g) ^ (lo & 7)) * 8;
  const int kro0 = lo * 128, kro1 = (16 + lo) * 128;
  const int vco = (g ^ (lo & 3)) * 8;

  const int gA = (g & 1) * 2;
  const int idx0 = lo + 16 * gA, idx1 = idx0 + 16;
  const bool hi = (g >= 2);

  {
    int4 ka = *(const int4*)(kS + (size_t)(kv_base + kr) * HEADD + kck * 8);
    int4 va = *(const int4*)(vS + (size_t)vr * S_LEN + kv_base + vck * 8);
    *(int4*)(&kt[0][kld]) = ka;
    *(int4*)(&vl[0][vld]) = va;
  }
  __syncthreads();

  int cur = 0;
#pragma unroll 1
  for (int it = 0; it < 16; ++it) {
    int4 ka, va;
    if (it + 1 < 16) {
      const int kvn = kv_base + (it + 1) * 32;
      ka = *(const int4*)(kS + (size_t)(kvn + kr) * HEADD + kck * 8);
      va = *(const int4*)(vS + (size_t)vr * S_LEN + kvn + vck * 8);
    }

    const short* kbase = &kt[cur][0];
    short8 a00 = *(const short8*)(kbase + kro0 + kc0);
    short8 a01 = *(const short8*)(kbase + kro0 + kc1);
    short8 a10 = *(const short8*)(kbase + kro1 + kc0);
    short8 a11 = *(const short8*)(kbase + kro1 + kc1);

    floatx4 z = floatx4{0.f, 0.f, 0.f, 0.f};
    floatx4 u;
    u = __builtin_amdgcn_mfma_f32_16x16x32_bf16(a00, qA0, z, 0, 0, 0);
    floatx4 T0A = __builtin_amdgcn_mfma_f32_16x16x32_bf16(a01, qA1, u, 0, 0, 0);
    u = __builtin_amdgcn_mfma_f32_16x16x32_bf16(a10, qA0, z, 0, 0, 0);
    floatx4 T1A = __builtin_amdgcn_mfma_f32_16x16x32_bf16(a11, qA1, u, 0, 0, 0);
    u = __builtin_amdgcn_mfma_f32_16x16x32_bf16(a00, qB0, z, 0, 0, 0);
    floatx4 T0B = __builtin_amdgcn_mfma_f32_16x16x32_bf16(a01, qB1, u, 0, 0, 0);
    u = __builtin_amdgcn_mfma_f32_16x16x32_bf16(a10, qB0, z, 0, 0, 0);
    floatx4 T1B = __builtin_amdgcn_mfma_f32_16x16x32_bf16(a11, qB1, u, 0, 0, 0);

    short8 paA, paB;
    {
      float p0 = __expf(T0A[0]), p1 = __expf(T0A[1]), p2 = __expf(T0A[2]), p3 = __expf(T0A[3]);
      float p4 = __expf(T1A[0]), p5 = __expf(T1A[1]), p6 = __expf(T1A[2]), p7 = __expf(T1A[3]);
      float lp = ((p0 + p1) + (p2 + p3)) + ((p4 + p5) + (p6 + p7));
      lp += __shfl_xor(lp, 16);
      lp += __shfl_xor(lp, 32);
      lxA += lp;
      int c00 = pkbf(p0, p1), c01 = pkbf(p2, p3);
      int c10 = pkbf(p4, p5), c11 = pkbf(p6, p7);
      int t0a = __shfl(c00, idx0), t0b = __shfl(c01, idx0);
      int t0c = __shfl(c00, idx1), t0d = __shfl(c01, idx1);
      int t1a = __shfl(c10, idx0), t1b = __shfl(c11, idx0);
      int t1c = __shfl(c10, idx1), t1d = __shfl(c11, idx1);
      int w0 = hi ? t1a : t0a, w1 = hi ? t1b : t0b;
      int w2 = hi ? t1c : t0c, w3 = hi ? t1d : t0d;
      int4 tmp = {w0, w1, w2, w3}; __builtin_memcpy(&paA, &tmp, 16);
    }
    {
      float p0 = __expf(T0B[0]), p1 = __expf(T0B[1]), p2 = __expf(T0B[2]), p3 = __expf(T0B[3]);
      float p4 = __expf(T1B[0]), p5 = __expf(T1B[1]), p6 = __expf(T1B[2]), p7 = __expf(T1B[3]);
      float lp = ((p0 + p1) + (p2 + p3)) + ((p4 + p5) + (p6 + p7));
      lp += __shfl_xor(lp, 16);
      lp += __shfl_xor(lp, 32);
      lxB += lp;
      int c00 = pkbf(p0, p1), c01 = pkbf(p2, p3);
      int c10 = pkbf(p4, p5), c11 = pkbf(p6, p7);
      int t0a = __shfl(c00, idx0), t0b = __shfl(c01, idx0);
      int t0c = __shfl(c00, idx1), t0d = __shfl(c01, idx1);
      int t1a = __shfl(c10, idx0), t1b = __shfl(c11, idx0);
      int t1c = __shfl(c10, idx1), t1d = __shfl(c11, idx1);
      int w0 = hi ? t1a : t0a, w1 = hi ? t1b : t0b;
      int w2 = hi ? t1c : t0c, w3 = hi ? t1d : t0d;
      int4 tmp = {w0, w1, w2, w3}; __builtin_memcpy(&paB, &tmp, 16);
    }

    const short* vbase = &vl[cur][0];
#pragma unroll
    for (int n = 0; n < 8; ++n) {
      short8 vf = *(const short8*)(vbase + (n * 16 + lo) * 32 + vco);
      accA[n] = __builtin_amdgcn_mfma_f32_16x16x32_bf16(paA, vf, accA[n], 0, 0, 0);
      accB[n] = __builtin_amdgcn_mfma_f32_16x16x32_bf16(paB, vf, accB[n], 0, 0, 0);
    }

    if (it + 1 < 16) {
      *(int4*)(&kt[cur ^ 1][kld]) = ka;
      *(int4*)(&vl[cur ^ 1][vld]) = va;
    }
    __syncthreads();
    cur ^= 1;
  }

  // packed bf16 partial stores (permuted cols c' = lo*8+n), no atomics
  short* pw = po + ((size_t)(ksp * 2 + s) * 8192) * 128;
#pragma unroll
  for (int j = 0; j < 4; ++j) {
    short8 pk;
#pragma unroll
    for (int n = 0; n < 8; ++n) pk[n] = f2bs(accA[n][j]);
    *(short8*)(pw + (size_t)(rowqA + g * 4 + j) * 128 + lo * 8) = pk;
#pragma unroll
    for (int n = 0; n < 8; ++n) pk[n] = f2bs(accB[n][j]);
    *(short8*)(pw + (size_t)(rowqB + g * 4 + j) * 128 + lo * 8) = pk;
  }
  if (g == 0) {
    pls[(size_t)(ksp * 2 + s) * 8192 + rowqA + lo] = lxA;
    pls[(size_t)(ksp * 2 + s) * 8192 + rowqB + lo] = lxB;
  }
}

// ---- Kernel 4: merge 8 ksp partials + diff combine + RMSNorm -> out (unchanged)
__global__ __launch_bounds__(256) void merge_kernel(const short* __restrict__ po,
                                                    const float* __restrict__ pls,
                                                    const float* __restrict__ lq1,
                                                    const float* __restrict__ lq2,
                                                    const float* __restrict__ lk1,
                                                    const float* __restrict__ lk2,
                                                    const float* __restrict__ rmsw,
                                                    float* __restrict__ out) {
  const int tid = threadIdx.x;
  const int row = blockIdx.x * 16 + (tid >> 4);
  const int lo = tid & 15;

  float a1s = 0.f, a2s = 0.f;
  for (int i = 0; i < 64; ++i) {
    a1s = fmaf(lq1[i], lk1[i], a1s);
    a2s = fmaf(lq2[i], lk2[i], a2s);
  }
  const float lam = __expf(a1s) - __expf(a2s) + 0.7836057665316245f;

  float o1[8], o2[8];
#pragma unroll
  for (int n = 0; n < 8; ++n) { o1[n] = 0.f; o2[n] = 0.f; }
  float l1 = 0.f, l2 = 0.f;
#pragma unroll
  for (int ksp = 0; ksp < 8; ++ksp) {
    short8 sa = *(const short8*)(po + ((size_t)(ksp * 2 + 0) * 8192 + row) * 128 + lo * 8);
    short8 sb = *(const short8*)(po + ((size_t)(ksp * 2 + 1) * 8192 + row) * 128 + lo * 8);
#pragma unroll
    for (int n = 0; n < 8; ++n) { o1[n] += bs2f(sa[n]); o2[n] += bs2f(sb[n]); }
    l1 += pls[(size_t)(ksp * 2 + 0) * 8192 + row];
    l2 += pls[(size_t)(ksp * 2 + 1) * 8192 + row];
  }
  const float iL1 = 1.f / l1, iL2 = 1.f / l2;

  float v[8];
  float ssq = 0.f;
#pragma unroll
  for (int n = 0; n < 8; ++n) {
    v[n] = o1[n] * iL1 - lam * (o2[n] * iL2);
    ssq += v[n] * v[n];
  }
  ssq += __shfl_xor(ssq, 1);
  ssq += __shfl_xor(ssq, 2);
  ssq += __shfl_xor(ssq, 4);
  ssq += __shfl_xor(ssq, 8);
  const float rr = rsqrtf(ssq * (1.f / 128.f) + 1.1920928955078125e-07f);

  float* ob = out + (size_t)row * 128;
#pragma unroll
  for (int n = 0; n < 8; ++n) {
    int c = n * 16 + lo;
    ob[c] = 0.21639423346837554f * v[n] * rr * rmsw[c];
  }
}

extern "C" void kernel_launch(void* const* d_in, const int* in_sizes, int n_in,
                              void* d_out, int out_size, void* d_ws, size_t ws_size,
                              hipStream_t stream) {
  const float* x   = (const float*)d_in[0];
  const float* wq  = (const float*)d_in[1];
  const float* wk  = (const float*)d_in[2];
  const float* wv  = (const float*)d_in[3];
  const float* lq1 = (const float*)d_in[4];
  const float* lq2 = (const float*)d_in[5];
  const float* lk1 = (const float*)d_in[6];
  const float* lk2 = (const float*)d_in[7];
  const float* rw  = (const float*)d_in[8];
  float* out = (float*)d_out;

  char* ws = (char*)d_ws;
  short* qm  = (short*)(ws);                        // 2 MB (q pre-scaled 0.125)
  short* kb  = (short*)(ws + (2u << 20));           // 2 MB
  short* vt  = (short*)(ws + (4u << 20));           // 2 MB (V^T [b][h][s])
  short* wc  = (short*)(ws + (6u << 20));           // 1.5 MB
  short* vstage = (short*)(ws + (6u << 20) + 1572864u); // 2 MB [8192][128]
  short* po  = (short*)(ws + (8u << 20));           // 32 MB [16][8192][128]
  float* pls = (float*)(ws + (40u << 20));          // 512 KB fp32 [16][8192]

  convw_kernel<<<768, 256, 0, stream>>>(wq, wk, wv, wc);
  proj_kernel<<<512, 256, 0, stream>>>(x, wc, qm, kb, vstage);
  conv_v_kernel<<<128, 256, 0, stream>>>(vstage, vt);
  attn_kernel<<<512, 512, 0, stream>>>(qm, kb, vt, po, pls);
  merge_kernel<<<512, 256, 0, stream>>>(po, pls, lq1, lq2, lk1, lk2, rw, out);
}

// Round 21
// 103.472 us; speedup vs baseline: 1.0047x; 1.0047x over previous
//
#include <hip/hip_runtime.h>
#include <hip/hip_bf16.h>
#include <math.h>

#define S_LEN 4096
#define DMODEL 2048
#define HEADD 128

typedef __attribute__((ext_vector_type(8))) short short8;
typedef __attribute__((ext_vector_type(4))) float floatx4;

__device__ __forceinline__ short f2bs(float f) {
  __hip_bfloat16 h = __float2bfloat16(f);
  short s; __builtin_memcpy(&s, &h, 2); return s;
}
__device__ __forceinline__ float bs2f(short s) {
  unsigned u = ((unsigned)(unsigned short)s) << 16;
  float f; __builtin_memcpy(&f, &u, 4); return f;
}
__device__ __forceinline__ int pkbf(float a, float b) {  // (lo=a, hi=b) bf16 pair
  return (int)(((unsigned)(unsigned short)f2bs(b) << 16) |
               (unsigned)(unsigned short)f2bs(a));
}

// ---- Kernel 1: convert Wq,Wk,Wv (fp32 [128][2048] each) -> wc bf16 [384][2048]
__global__ __launch_bounds__(256) void convw_kernel(const float* __restrict__ wq,
                                                    const float* __restrict__ wk,
                                                    const float* __restrict__ wv,
                                                    short* __restrict__ wc) {
  const int per = 128 * 2048;
  int e = (blockIdx.x * blockDim.x + threadIdx.x) * 4;
  const float* src = (e < per) ? wq : (e < 2 * per) ? wk : wv;
  int off = e & (per - 1);
  float4 v = *(const float4*)(src + off);
  short4 r;
  r.x = f2bs(v.x); r.y = f2bs(v.y); r.z = f2bs(v.z); r.w = f2bs(v.w);
  *(short4*)(wc + e) = r;
}

// ---- Kernel 2: projection GEMM (R19 structure; q pre-scale now includes
// log2(e) so attn can use native exp2 -- saves 16 v_mul per wave-iter there)
__global__ __launch_bounds__(256, 3) void proj_kernel(const float* __restrict__ x,
                                                      const short* __restrict__ wc,
                                                      short* __restrict__ qm,
                                                      short* __restrict__ kb,
                                                      short* __restrict__ vstage) {
  const int tid = threadIdx.x;
  const int w = tid >> 6;
  const int lane = tid & 63;
  const int lo = lane & 15, g = lane >> 4;
  const int id = blockIdx.x;
  const int nq = id >> 7, mb = id & 127;
  const int m0 = mb * 64;
  const int n0 = nq * 96;

  __shared__ short xt[2][64 * 64];
  __shared__ short wt[2][96 * 64];

  const int r8 = tid >> 3, sc = tid & 7;
  const float* xs0 = x + (size_t)(m0 + r8) * DMODEL + sc * 8;
  const float* xs1 = x + (size_t)(m0 + 32 + r8) * DMODEL + sc * 8;
  const short* ws0 = wc + (size_t)(n0 + r8) * DMODEL + sc * 8;
  const short* ws1 = wc + (size_t)(n0 + 32 + r8) * DMODEL + sc * 8;
  const short* ws2 = wc + (size_t)(n0 + 64 + r8) * DMODEL + sc * 8;
  const int xl0 = r8 * 64 + ((sc ^ (r8 & 7)) * 8);
  const int xl1 = (32 + r8) * 64 + ((sc ^ (r8 & 7)) * 8);
  const int wlo0 = r8 * 64 + ((sc ^ (r8 & 7)) * 8);
  const int wlo1 = (32 + r8) * 64 + ((sc ^ (r8 & 7)) * 8);
  const int wlo2 = (64 + r8) * 64 + ((sc ^ (r8 & 7)) * 8);

  const int mrow = (w >> 1) * 32;
  const int ncol = (w & 1) * 48;
  int aoff[2][2], boff[3][2];
#pragma unroll
  for (int mi = 0; mi < 2; ++mi) {
    int r = mrow + mi * 16 + lo;
#pragma unroll
    for (int kc = 0; kc < 2; ++kc)
      aoff[mi][kc] = r * 64 + (((kc * 4 + g) ^ (r & 7)) * 8);
  }
#pragma unroll
  for (int t = 0; t < 3; ++t) {
    int r = ncol + t * 16 + lo;
#pragma unroll
    for (int kc = 0; kc < 2; ++kc)
      boff[t][kc] = r * 64 + (((kc * 4 + g) ^ (r & 7)) * 8);
  }

  floatx4 acc[2][3];
#pragma unroll
  for (int mi = 0; mi < 2; ++mi)
#pragma unroll
    for (int t = 0; t < 3; ++t) acc[mi][t] = floatx4{0.f, 0.f, 0.f, 0.f};

  {
    float4 a0 = *(const float4*)(xs0), a1 = *(const float4*)(xs0 + 4);
    float4 b0 = *(const float4*)(xs1), b1 = *(const float4*)(xs1 + 4);
    int4 w0 = *(const int4*)(ws0);
    int4 w1 = *(const int4*)(ws1);
    int4 w2 = *(const int4*)(ws2);
    short8 sA, sB;
    sA[0]=f2bs(a0.x); sA[1]=f2bs(a0.y); sA[2]=f2bs(a0.z); sA[3]=f2bs(a0.w);
    sA[4]=f2bs(a1.x); sA[5]=f2bs(a1.y); sA[6]=f2bs(a1.z); sA[7]=f2bs(a1.w);
    sB[0]=f2bs(b0.x); sB[1]=f2bs(b0.y); sB[2]=f2bs(b0.z); sB[3]=f2bs(b0.w);
    sB[4]=f2bs(b1.x); sB[5]=f2bs(b1.y); sB[6]=f2bs(b1.z); sB[7]=f2bs(b1.w);
    *(short8*)&xt[0][xl0] = sA;
    *(short8*)&xt[0][xl1] = sB;
    *(int4*)&wt[0][wlo0] = w0;
    *(int4*)&wt[0][wlo1] = w1;
    *(int4*)&wt[0][wlo2] = w2;
  }
  __syncthreads();

  int cur = 0;
#pragma unroll 1
  for (int it = 0; it < 32; ++it) {
    float4 a0, a1, b0, b1;
    int4 w0, w1, w2;
    if (it + 1 < 32) {
      const int k = (it + 1) * 64;
      a0 = *(const float4*)(xs0 + k); a1 = *(const float4*)(xs0 + k + 4);
      b0 = *(const float4*)(xs1 + k); b1 = *(const float4*)(xs1 + k + 4);
      w0 = *(const int4*)(ws0 + k);
      w1 = *(const int4*)(ws1 + k);
      w2 = *(const int4*)(ws2 + k);
    }

    {
      const short* xb = &xt[cur][0];
      const short* wb = &wt[cur][0];
      short8 af[2][2], bf[3][2];
#pragma unroll
      for (int mi = 0; mi < 2; ++mi)
#pragma unroll
        for (int kc = 0; kc < 2; ++kc) af[mi][kc] = *(const short8*)(xb + aoff[mi][kc]);
#pragma unroll
      for (int t = 0; t < 3; ++t)
#pragma unroll
        for (int kc = 0; kc < 2; ++kc) bf[t][kc] = *(const short8*)(wb + boff[t][kc]);
#pragma unroll
      for (int kc = 0; kc < 2; ++kc)
#pragma unroll
        for (int mi = 0; mi < 2; ++mi)
#pragma unroll
          for (int t = 0; t < 3; ++t)
            acc[mi][t] = __builtin_amdgcn_mfma_f32_16x16x32_bf16(af[mi][kc], bf[t][kc], acc[mi][t], 0, 0, 0);
    }

    if (it + 1 < 32) {
      short8 sA, sB;
      sA[0]=f2bs(a0.x); sA[1]=f2bs(a0.y); sA[2]=f2bs(a0.z); sA[3]=f2bs(a0.w);
      sA[4]=f2bs(a1.x); sA[5]=f2bs(a1.y); sA[6]=f2bs(a1.z); sA[7]=f2bs(a1.w);
      sB[0]=f2bs(b0.x); sB[1]=f2bs(b0.y); sB[2]=f2bs(b0.z); sB[3]=f2bs(b0.w);
      sB[4]=f2bs(b1.x); sB[5]=f2bs(b1.y); sB[6]=f2bs(b1.z); sB[7]=f2bs(b1.w);
      *(short8*)&xt[cur ^ 1][xl0] = sA;
      *(short8*)&xt[cur ^ 1][xl1] = sB;
      *(int4*)&wt[cur ^ 1][wlo0] = w0;
      *(int4*)&wt[cur ^ 1][wlo1] = w1;
      *(int4*)&wt[cur ^ 1][wlo2] = w2;
    }
    __syncthreads();
    cur ^= 1;
  }

#pragma unroll
  for (int t = 0; t < 3; ++t) {
    int n = n0 + ncol + t * 16 + lo;
#pragma unroll
    for (int mi = 0; mi < 2; ++mi)
#pragma unroll
      for (int j = 0; j < 4; ++j) {
        int m = m0 + mrow + mi * 16 + g * 4 + j;
        float v = acc[mi][t][j];
        if (n < HEADD) {
          // 0.125 * log2(e): attn uses native exp2
          qm[(size_t)m * HEADD + n] = f2bs(v * 0.18033688011112042f);
        } else if (n < 2 * HEADD) {
          kb[(size_t)m * HEADD + (n - HEADD)] = f2bs(v);
        } else {
          vstage[(size_t)m * HEADD + (n - 2 * HEADD)] = f2bs(v);
        }
      }
  }
}

// ---- Kernel 2c: vstage[8192][128] -> vt[b][h][s] via LDS transpose
__global__ __launch_bounds__(256) void conv_v_kernel(const short* __restrict__ vstage,
                                                     short* __restrict__ vt) {
  const int tid = threadIdx.x;
  const int bb = blockIdx.x >> 6, st = blockIdx.x & 63;
  const int s0 = st * 64;

  __shared__ short ld[64][136];

  const int r = tid >> 2, c8 = (tid & 3) * 32;
#pragma unroll
  for (int q = 0; q < 4; ++q) {
    const size_t off = (size_t)(bb * 4096 + s0 + r) * 128 + c8 + q * 8;
    *(short8*)(&ld[r][c8 + q * 8]) = *(const short8*)(vstage + off);
  }
  __syncthreads();

  const int h = tid >> 1, sh = (tid & 1) * 32;
#pragma unroll
  for (int q = 0; q < 4; ++q) {
    short8 t;
#pragma unroll
    for (int i = 0; i < 8; ++i) t[i] = ld[sh + q * 8 + i][h];
    *(short8*)(vt + ((size_t)bb * 128 + h) * 4096 + s0 + sh + q * 8) = t;
  }
}

// ---- Kernel 3: LDS-staged flash attention (R19 config restored: 256 thr,
// grid 1024 = 128 qblk x 8 ksp, (256,3); R20's 8-wave blocks regressed).
// exp2f replaces __expf (log2e folded into qm).
__global__ __launch_bounds__(256, 3) void attn_kernel(const short* __restrict__ qm,
                                                      const short* __restrict__ kb,
                                                      const short* __restrict__ vt,
                                                      short* __restrict__ po,
                                                      float* __restrict__ pls) {
  const int tid = threadIdx.x;
  const int w = tid >> 6;
  const int lane = tid & 63;
  const int lo = lane & 15, g = lane >> 4;
  const int qsp = w >> 1;
  const int s = w & 1;
  const int id = blockIdx.x;
  const int ksp = id & 7;
  const int qblk = id >> 3;
  const int b = qblk >> 6;
  const int kv_base = ksp * 512;

  __shared__ short kt[2][32 * 128];
  __shared__ short vl[2][128 * 32];

  const int kr0 = tid >> 4, kck = tid & 15;
  const int vr0 = tid >> 2, vck = tid & 3;
  const short* kS = kb + (size_t)b * S_LEN * HEADD;
  const short* vS = vt + (size_t)b * HEADD * S_LEN;
  const int kld0 = kr0 * 128 + ((kck ^ (kr0 & 7)) * 8);
  const int kld1 = (kr0 + 16) * 128 + ((kck ^ (kr0 & 7)) * 8);
  const int vld0 = vr0 * 32 + ((vck ^ (vr0 & 3)) * 8);
  const int vld1 = (vr0 + 64) * 32 + ((vck ^ (vr0 & 3)) * 8);

  const int rowqA = qblk * 64 + qsp * 32;
  const int rowqB = rowqA + 16;
  const short* qrowA = qm + (size_t)(rowqA + lo) * HEADD + s * 64;
  const short* qrowB = qm + (size_t)(rowqB + lo) * HEADD + s * 64;
  const short8 qA0 = *(const short8*)(qrowA + g * 8);
  const short8 qA1 = *(const short8*)(qrowA + 32 + g * 8);
  const short8 qB0 = *(const short8*)(qrowB + g * 8);
  const short8 qB1 = *(const short8*)(qrowB + 32 + g * 8);

  floatx4 accA[8], accB[8];
#pragma unroll
  for (int n = 0; n < 8; ++n) {
    accA[n] = floatx4{0.f, 0.f, 0.f, 0.f};
    accB[n] = floatx4{0.f, 0.f, 0.f, 0.f};
  }
  float lxA = 0.f, lxB = 0.f;

  const int kc0 = ((s * 8 + g) ^ (lo & 7)) * 8;
  const int kc1 = ((s * 8 + 4 + g) ^ (lo & 7)) * 8;
  const int kro0 = lo * 128, kro1 = (16 + lo) * 128;
  const int vco = (g ^ (lo & 3)) * 8;

  const int gA = (g & 1) * 2;
  const int idx0 = lo + 16 * gA, idx1 = idx0 + 16;
  const bool hi = (g >= 2);

  {
    int4 ka = *(const int4*)(kS + (size_t)(kv_base + kr0) * HEADD + kck * 8);
    int4 kbx = *(const int4*)(kS + (size_t)(kv_base + kr0 + 16) * HEADD + kck * 8);
    int4 va = *(const int4*)(vS + (size_t)vr0 * S_LEN + kv_base + vck * 8);
    int4 vb = *(const int4*)(vS + (size_t)(vr0 + 64) * S_LEN + kv_base + vck * 8);
    *(int4*)(&kt[0][kld0]) = ka;
    *(int4*)(&kt[0][kld1]) = kbx;
    *(int4*)(&vl[0][vld0]) = va;
    *(int4*)(&vl[0][vld1]) = vb;
  }
  __syncthreads();

  int cur = 0;
#pragma unroll 1
  for (int it = 0; it < 16; ++it) {
    int4 ka, kbx, va, vb;
    if (it + 1 < 16) {
      const int kvn = kv_base + (it + 1) * 32;
      ka  = *(const int4*)(kS + (size_t)(kvn + kr0) * HEADD + kck * 8);
      kbx = *(const int4*)(kS + (size_t)(kvn + kr0 + 16) * HEADD + kck * 8);
      va  = *(const int4*)(vS + (size_t)vr0 * S_LEN + kvn + vck * 8);
      vb  = *(const int4*)(vS + (size_t)(vr0 + 64) * S_LEN + kvn + vck * 8);
    }

    const short* kbase = &kt[cur][0];
    short8 a00 = *(const short8*)(kbase + kro0 + kc0);
    short8 a01 = *(const short8*)(kbase + kro0 + kc1);
    short8 a10 = *(const short8*)(kbase + kro1 + kc0);
    short8 a11 = *(const short8*)(kbase + kro1 + kc1);

    floatx4 z = floatx4{0.f, 0.f, 0.f, 0.f};
    floatx4 u;
    u = __builtin_amdgcn_mfma_f32_16x16x32_bf16(a00, qA0, z, 0, 0, 0);
    floatx4 T0A = __builtin_amdgcn_mfma_f32_16x16x32_bf16(a01, qA1, u, 0, 0, 0);
    u = __builtin_amdgcn_mfma_f32_16x16x32_bf16(a10, qA0, z, 0, 0, 0);
    floatx4 T1A = __builtin_amdgcn_mfma_f32_16x16x32_bf16(a11, qA1, u, 0, 0, 0);
    u = __builtin_amdgcn_mfma_f32_16x16x32_bf16(a00, qB0, z, 0, 0, 0);
    floatx4 T0B = __builtin_amdgcn_mfma_f32_16x16x32_bf16(a01, qB1, u, 0, 0, 0);
    u = __builtin_amdgcn_mfma_f32_16x16x32_bf16(a10, qB0, z, 0, 0, 0);
    floatx4 T1B = __builtin_amdgcn_mfma_f32_16x16x32_bf16(a11, qB1, u, 0, 0, 0);

    short8 paA, paB;
    {
      float p0 = exp2f(T0A[0]), p1 = exp2f(T0A[1]), p2 = exp2f(T0A[2]), p3 = exp2f(T0A[3]);
      float p4 = exp2f(T1A[0]), p5 = exp2f(T1A[1]), p6 = exp2f(T1A[2]), p7 = exp2f(T1A[3]);
      float lp = ((p0 + p1) + (p2 + p3)) + ((p4 + p5) + (p6 + p7));
      lp += __shfl_xor(lp, 16);
      lp += __shfl_xor(lp, 32);
      lxA += lp;
      int c00 = pkbf(p0, p1), c01 = pkbf(p2, p3);
      int c10 = pkbf(p4, p5), c11 = pkbf(p6, p7);
      int t0a = __shfl(c00, idx0), t0b = __shfl(c01, idx0);
      int t0c = __shfl(c00, idx1), t0d = __shfl(c01, idx1);
      int t1a = __shfl(c10, idx0), t1b = __shfl(c11, idx0);
      int t1c = __shfl(c10, idx1), t1d = __shfl(c11, idx1);
      int w0 = hi ? t1a : t0a, w1 = hi ? t1b : t0b;
      int w2 = hi ? t1c : t0c, w3 = hi ? t1d : t0d;
      int4 tmp = {w0, w1, w2, w3}; __builtin_memcpy(&paA, &tmp, 16);
    }
    {
      float p0 = exp2f(T0B[0]), p1 = exp2f(T0B[1]), p2 = exp2f(T0B[2]), p3 = exp2f(T0B[3]);
      float p4 = exp2f(T1B[0]), p5 = exp2f(T1B[1]), p6 = exp2f(T1B[2]), p7 = exp2f(T1B[3]);
      float lp = ((p0 + p1) + (p2 + p3)) + ((p4 + p5) + (p6 + p7));
      lp += __shfl_xor(lp, 16);
      lp += __shfl_xor(lp, 32);
      lxB += lp;
      int c00 = pkbf(p0, p1), c01 = pkbf(p2, p3);
      int c10 = pkbf(p4, p5), c11 = pkbf(p6, p7);
      int t0a = __shfl(c00, idx0), t0b = __shfl(c01, idx0);
      int t0c = __shfl(c00, idx1), t0d = __shfl(c01, idx1);
      int t1a = __shfl(c10, idx0), t1b = __shfl(c11, idx0);
      int t1c = __shfl(c10, idx1), t1d = __shfl(c11, idx1);
      int w0 = hi ? t1a : t0a, w1 = hi ? t1b : t0b;
      int w2 = hi ? t1c : t0c, w3 = hi ? t1d : t0d;
      int4 tmp = {w0, w1, w2, w3}; __builtin_memcpy(&paB, &tmp, 16);
    }

    const short* vbase = &vl[cur][0];
#pragma unroll
    for (int n = 0; n < 8; ++n) {
      short8 vf = *(const short8*)(vbase + (n * 16 + lo) * 32 + vco);
      accA[n] = __builtin_amdgcn_mfma_f32_16x16x32_bf16(paA, vf, accA[n], 0, 0, 0);
      accB[n] = __builtin_amdgcn_mfma_f32_16x16x32_bf16(paB, vf, accB[n], 0, 0, 0);
    }

    if (it + 1 < 16) {
      *(int4*)(&kt[cur ^ 1][kld0]) = ka;
      *(int4*)(&kt[cur ^ 1][kld1]) = kbx;
      *(int4*)(&vl[cur ^ 1][vld0]) = va;
      *(int4*)(&vl[cur ^ 1][vld1]) = vb;
    }
    __syncthreads();
    cur ^= 1;
  }

  short* pw = po + ((size_t)(ksp * 2 + s) * 8192) * 128;
#pragma unroll
  for (int j = 0; j < 4; ++j) {
    short8 pk;
#pragma unroll
    for (int n = 0; n < 8; ++n) pk[n] = f2bs(accA[n][j]);
    *(short8*)(pw + (size_t)(rowqA + g * 4 + j) * 128 + lo * 8) = pk;
#pragma unroll
    for (int n = 0; n < 8; ++n) pk[n] = f2bs(accB[n][j]);
    *(short8*)(pw + (size_t)(rowqB + g * 4 + j) * 128 + lo * 8) = pk;
  }
  if (g == 0) {
    pls[(size_t)(ksp * 2 + s) * 8192 + rowqA + lo] = lxA;
    pls[(size_t)(ksp * 2 + s) * 8192 + rowqB + lo] = lxB;
  }
}

// ---- Kernel 4: merge 8 ksp partials + diff combine + RMSNorm -> out (unchanged)
__global__ __launch_bounds__(256) void merge_kernel(const short* __restrict__ po,
                                                    const float* __restrict__ pls,
                                                    const float* __restrict__ lq1,
                                                    const float* __restrict__ lq2,
                                                    const float* __restrict__ lk1,
                                                    const float* __restrict__ lk2,
                                                    const float* __restrict__ rmsw,
                                                    float* __restrict__ out) {
  const int tid = threadIdx.x;
  const int row = blockIdx.x * 16 + (tid >> 4);
  const int lo = tid & 15;

  float a1s = 0.f, a2s = 0.f;
  for (int i = 0; i < 64; ++i) {
    a1s = fmaf(lq1[i], lk1[i], a1s);
    a2s = fmaf(lq2[i], lk2[i], a2s);
  }
  const float lam = __expf(a1s) - __expf(a2s) + 0.7836057665316245f;

  float o1[8], o2[8];
#pragma unroll
  for (int n = 0; n < 8; ++n) { o1[n] = 0.f; o2[n] = 0.f; }
  float l1 = 0.f, l2 = 0.f;
#pragma unroll
  for (int ksp = 0; ksp < 8; ++ksp) {
    short8 sa = *(const short8*)(po + ((size_t)(ksp * 2 + 0) * 8192 + row) * 128 + lo * 8);
    short8 sb = *(const short8*)(po + ((size_t)(ksp * 2 + 1) * 8192 + row) * 128 + lo * 8);
#pragma unroll
    for (int n = 0; n < 8; ++n) { o1[n] += bs2f(sa[n]); o2[n] += bs2f(sb[n]); }
    l1 += pls[(size_t)(ksp * 2 + 0) * 8192 + row];
    l2 += pls[(size_t)(ksp * 2 + 1) * 8192 + row];
  }
  const float iL1 = 1.f / l1, iL2 = 1.f / l2;

  float v[8];
  float ssq = 0.f;
#pragma unroll
  for (int n = 0; n < 8; ++n) {
    v[n] = o1[n] * iL1 - lam * (o2[n] * iL2);
    ssq += v[n] * v[n];
  }
  ssq += __shfl_xor(ssq, 1);
  ssq += __shfl_xor(ssq, 2);
  ssq += __shfl_xor(ssq, 4);
  ssq += __shfl_xor(ssq, 8);
  const float rr = rsqrtf(ssq * (1.f / 128.f) + 1.1920928955078125e-07f);

  float* ob = out + (size_t)row * 128;
#pragma unroll
  for (int n = 0; n < 8; ++n) {
    int c = n * 16 + lo;
    ob[c] = 0.21639423346837554f * v[n] * rr * rmsw[c];
  }
}

extern "C" void kernel_launch(void* const* d_in, const int* in_sizes, int n_in,
                              void* d_out, int out_size, void* d_ws, size_t ws_size,
                              hipStream_t stream) {
  const float* x   = (const float*)d_in[0];
  const float* wq  = (const float*)d_in[1];
  const float* wk  = (const float*)d_in[2];
  const float* wv  = (const float*)d_in[3];
  const float* lq1 = (const float*)d_in[4];
  const float* lq2 = (const float*)d_in[5];
  const float* lk1 = (const float*)d_in[6];
  const float* lk2 = (const float*)d_in[7];
  const float* rw  = (const float*)d_in[8];
  float* out = (float*)d_out;

  char* ws = (char*)d_ws;
  short* qm  = (short*)(ws);                        // 2 MB (q pre-scaled 0.125*log2e)
  short* kb  = (short*)(ws + (2u << 20));           // 2 MB
  short* vt  = (short*)(ws + (4u << 20));           // 2 MB (V^T [b][h][s])
  short* wc  = (short*)(ws + (6u << 20));           // 1.5 MB
  short* vstage = (short*)(ws + (6u << 20) + 1572864u); // 2 MB [8192][128]
  short* po  = (short*)(ws + (8u << 20));           // 32 MB [16][8192][128]
  float* pls = (float*)(ws + (40u << 20));          // 512 KB fp32 [16][8192]

  convw_kernel<<<768, 256, 0, stream>>>(wq, wk, wv, wc);
  proj_kernel<<<512, 256, 0, stream>>>(x, wc, qm, kb, vstage);
  conv_v_kernel<<<128, 256, 0, stream>>>(vstage, vt);
  attn_kernel<<<1024, 256, 0, stream>>>(qm, kb, vt, po, pls);
  merge_kernel<<<512, 256, 0, stream>>>(po, pls, lq1, lq2, lk1, lk2, rw, out);
}

// Round 22
// 96.641 us; speedup vs baseline: 1.0758x; 1.0707x over previous
//
#include <hip/hip_runtime.h>
#include <hip/hip_bf16.h>
#include <math.h>

#define S_LEN 4096
#define DMODEL 2048
#define HEADD 128

typedef __attribute__((ext_vector_type(8))) short short8;
typedef __attribute__((ext_vector_type(4))) float floatx4;

__device__ __forceinline__ short f2bs(float f) {
  __hip_bfloat16 h = __float2bfloat16(f);
  short s; __builtin_memcpy(&s, &h, 2); return s;
}
__device__ __forceinline__ float bs2f(short s) {
  unsigned u = ((unsigned)(unsigned short)s) << 16;
  float f; __builtin_memcpy(&f, &u, 4); return f;
}
__device__ __forceinline__ int pkbf(float a, float b) {  // (lo=a, hi=b) bf16 pair
  return (int)(((unsigned)(unsigned short)f2bs(b) << 16) |
               (unsigned)(unsigned short)f2bs(a));
}
// raw v_exp_f32: 2^x, no libm guard code (R21 lesson: exp2f = slow libm path)
__device__ __forceinline__ float fexp2(float x) { return __builtin_amdgcn_exp2f(x); }

// ---- Kernel 1: convert Wq,Wk,Wv (fp32 [128][2048] each) -> wc bf16 [384][2048]
__global__ __launch_bounds__(256) void convw_kernel(const float* __restrict__ wq,
                                                    const float* __restrict__ wk,
                                                    const float* __restrict__ wv,
                                                    short* __restrict__ wc) {
  const int per = 128 * 2048;
  int e = (blockIdx.x * blockDim.x + threadIdx.x) * 4;
  const float* src = (e < per) ? wq : (e < 2 * per) ? wk : wv;
  int off = e & (per - 1);
  float4 v = *(const float4*)(src + off);
  short4 r;
  r.x = f2bs(v.x); r.y = f2bs(v.y); r.z = f2bs(v.z); r.w = f2bs(v.w);
  *(short4*)(wc + e) = r;
}

// ---- Kernel 2: projection GEMM (R19 structure; q pre-scale includes log2(e))
__global__ __launch_bounds__(256, 3) void proj_kernel(const float* __restrict__ x,
                                                      const short* __restrict__ wc,
                                                      short* __restrict__ qm,
                                                      short* __restrict__ kb,
                                                      short* __restrict__ vstage) {
  const int tid = threadIdx.x;
  const int w = tid >> 6;
  const int lane = tid & 63;
  const int lo = lane & 15, g = lane >> 4;
  const int id = blockIdx.x;
  const int nq = id >> 7, mb = id & 127;
  const int m0 = mb * 64;
  const int n0 = nq * 96;

  __shared__ short xt[2][64 * 64];
  __shared__ short wt[2][96 * 64];

  const int r8 = tid >> 3, sc = tid & 7;
  const float* xs0 = x + (size_t)(m0 + r8) * DMODEL + sc * 8;
  const float* xs1 = x + (size_t)(m0 + 32 + r8) * DMODEL + sc * 8;
  const short* ws0 = wc + (size_t)(n0 + r8) * DMODEL + sc * 8;
  const short* ws1 = wc + (size_t)(n0 + 32 + r8) * DMODEL + sc * 8;
  const short* ws2 = wc + (size_t)(n0 + 64 + r8) * DMODEL + sc * 8;
  const int xl0 = r8 * 64 + ((sc ^ (r8 & 7)) * 8);
  const int xl1 = (32 + r8) * 64 + ((sc ^ (r8 & 7)) * 8);
  const int wlo0 = r8 * 64 + ((sc ^ (r8 & 7)) * 8);
  const int wlo1 = (32 + r8) * 64 + ((sc ^ (r8 & 7)) * 8);
  const int wlo2 = (64 + r8) * 64 + ((sc ^ (r8 & 7)) * 8);

  const int mrow = (w >> 1) * 32;
  const int ncol = (w & 1) * 48;
  int aoff[2][2], boff[3][2];
#pragma unroll
  for (int mi = 0; mi < 2; ++mi) {
    int r = mrow + mi * 16 + lo;
#pragma unroll
    for (int kc = 0; kc < 2; ++kc)
      aoff[mi][kc] = r * 64 + (((kc * 4 + g) ^ (r & 7)) * 8);
  }
#pragma unroll
  for (int t = 0; t < 3; ++t) {
    int r = ncol + t * 16 + lo;
#pragma unroll
    for (int kc = 0; kc < 2; ++kc)
      boff[t][kc] = r * 64 + (((kc * 4 + g) ^ (r & 7)) * 8);
  }

  floatx4 acc[2][3];
#pragma unroll
  for (int mi = 0; mi < 2; ++mi)
#pragma unroll
    for (int t = 0; t < 3; ++t) acc[mi][t] = floatx4{0.f, 0.f, 0.f, 0.f};

  {
    float4 a0 = *(const float4*)(xs0), a1 = *(const float4*)(xs0 + 4);
    float4 b0 = *(const float4*)(xs1), b1 = *(const float4*)(xs1 + 4);
    int4 w0 = *(const int4*)(ws0);
    int4 w1 = *(const int4*)(ws1);
    int4 w2 = *(const int4*)(ws2);
    short8 sA, sB;
    sA[0]=f2bs(a0.x); sA[1]=f2bs(a0.y); sA[2]=f2bs(a0.z); sA[3]=f2bs(a0.w);
    sA[4]=f2bs(a1.x); sA[5]=f2bs(a1.y); sA[6]=f2bs(a1.z); sA[7]=f2bs(a1.w);
    sB[0]=f2bs(b0.x); sB[1]=f2bs(b0.y); sB[2]=f2bs(b0.z); sB[3]=f2bs(b0.w);
    sB[4]=f2bs(b1.x); sB[5]=f2bs(b1.y); sB[6]=f2bs(b1.z); sB[7]=f2bs(b1.w);
    *(short8*)&xt[0][xl0] = sA;
    *(short8*)&xt[0][xl1] = sB;
    *(int4*)&wt[0][wlo0] = w0;
    *(int4*)&wt[0][wlo1] = w1;
    *(int4*)&wt[0][wlo2] = w2;
  }
  __syncthreads();

  int cur = 0;
#pragma unroll 1
  for (int it = 0; it < 32; ++it) {
    float4 a0, a1, b0, b1;
    int4 w0, w1, w2;
    if (it + 1 < 32) {
      const int k = (it + 1) * 64;
      a0 = *(const float4*)(xs0 + k); a1 = *(const float4*)(xs0 + k + 4);
      b0 = *(const float4*)(xs1 + k); b1 = *(const float4*)(xs1 + k + 4);
      w0 = *(const int4*)(ws0 + k);
      w1 = *(const int4*)(ws1 + k);
      w2 = *(const int4*)(ws2 + k);
    }

    {
      const short* xb = &xt[cur][0];
      const short* wb = &wt[cur][0];
      short8 af[2][2], bf[3][2];
#pragma unroll
      for (int mi = 0; mi < 2; ++mi)
#pragma unroll
        for (int kc = 0; kc < 2; ++kc) af[mi][kc] = *(const short8*)(xb + aoff[mi][kc]);
#pragma unroll
      for (int t = 0; t < 3; ++t)
#pragma unroll
        for (int kc = 0; kc < 2; ++kc) bf[t][kc] = *(const short8*)(wb + boff[t][kc]);
#pragma unroll
      for (int kc = 0; kc < 2; ++kc)
#pragma unroll
        for (int mi = 0; mi < 2; ++mi)
#pragma unroll
          for (int t = 0; t < 3; ++t)
            acc[mi][t] = __builtin_amdgcn_mfma_f32_16x16x32_bf16(af[mi][kc], bf[t][kc], acc[mi][t], 0, 0, 0);
    }

    if (it + 1 < 32) {
      short8 sA, sB;
      sA[0]=f2bs(a0.x); sA[1]=f2bs(a0.y); sA[2]=f2bs(a0.z); sA[3]=f2bs(a0.w);
      sA[4]=f2bs(a1.x); sA[5]=f2bs(a1.y); sA[6]=f2bs(a1.z); sA[7]=f2bs(a1.w);
      sB[0]=f2bs(b0.x); sB[1]=f2bs(b0.y); sB[2]=f2bs(b0.z); sB[3]=f2bs(b0.w);
      sB[4]=f2bs(b1.x); sB[5]=f2bs(b1.y); sB[6]=f2bs(b1.z); sB[7]=f2bs(b1.w);
      *(short8*)&xt[cur ^ 1][xl0] = sA;
      *(short8*)&xt[cur ^ 1][xl1] = sB;
      *(int4*)&wt[cur ^ 1][wlo0] = w0;
      *(int4*)&wt[cur ^ 1][wlo1] = w1;
      *(int4*)&wt[cur ^ 1][wlo2] = w2;
    }
    __syncthreads();
    cur ^= 1;
  }

#pragma unroll
  for (int t = 0; t < 3; ++t) {
    int n = n0 + ncol + t * 16 + lo;
#pragma unroll
    for (int mi = 0; mi < 2; ++mi)
#pragma unroll
      for (int j = 0; j < 4; ++j) {
        int m = m0 + mrow + mi * 16 + g * 4 + j;
        float v = acc[mi][t][j];
        if (n < HEADD) {
          // 0.125 * log2(e): attn uses native v_exp_f32 (2^x)
          qm[(size_t)m * HEADD + n] = f2bs(v * 0.18033688011112042f);
        } else if (n < 2 * HEADD) {
          kb[(size_t)m * HEADD + (n - HEADD)] = f2bs(v);
        } else {
          vstage[(size_t)m * HEADD + (n - 2 * HEADD)] = f2bs(v);
        }
      }
  }
}

// ---- Kernel 2c: vstage[8192][128] -> vt[b][h][s] via LDS transpose
__global__ __launch_bounds__(256) void conv_v_kernel(const short* __restrict__ vstage,
                                                     short* __restrict__ vt) {
  const int tid = threadIdx.x;
  const int bb = blockIdx.x >> 6, st = blockIdx.x & 63;
  const int s0 = st * 64;

  __shared__ short ld[64][136];

  const int r = tid >> 2, c8 = (tid & 3) * 32;
#pragma unroll
  for (int q = 0; q < 4; ++q) {
    const size_t off = (size_t)(bb * 4096 + s0 + r) * 128 + c8 + q * 8;
    *(short8*)(&ld[r][c8 + q * 8]) = *(const short8*)(vstage + off);
  }
  __syncthreads();

  const int h = tid >> 1, sh = (tid & 1) * 32;
#pragma unroll
  for (int q = 0; q < 4; ++q) {
    short8 t;
#pragma unroll
    for (int i = 0; i < 8; ++i) t[i] = ld[sh + q * 8 + i][h];
    *(short8*)(vt + ((size_t)bb * 128 + h) * 4096 + s0 + sh + q * 8) = t;
  }
}

// ---- Kernel 3: LDS-staged flash attention (R19 config; raw v_exp_f32)
__global__ __launch_bounds__(256, 3) void attn_kernel(const short* __restrict__ qm,
                                                      const short* __restrict__ kb,
                                                      const short* __restrict__ vt,
                                                      short* __restrict__ po,
                                                      float* __restrict__ pls) {
  const int tid = threadIdx.x;
  const int w = tid >> 6;
  const int lane = tid & 63;
  const int lo = lane & 15, g = lane >> 4;
  const int qsp = w >> 1;
  const int s = w & 1;
  const int id = blockIdx.x;
  const int ksp = id & 7;
  const int qblk = id >> 3;
  const int b = qblk >> 6;
  const int kv_base = ksp * 512;

  __shared__ short kt[2][32 * 128];
  __shared__ short vl[2][128 * 32];

  const int kr0 = tid >> 4, kck = tid & 15;
  const int vr0 = tid >> 2, vck = tid & 3;
  const short* kS = kb + (size_t)b * S_LEN * HEADD;
  const short* vS = vt + (size_t)b * HEADD * S_LEN;
  const int kld0 = kr0 * 128 + ((kck ^ (kr0 & 7)) * 8);
  const int kld1 = (kr0 + 16) * 128 + ((kck ^ (kr0 & 7)) * 8);
  const int vld0 = vr0 * 32 + ((vck ^ (vr0 & 3)) * 8);
  const int vld1 = (vr0 + 64) * 32 + ((vck ^ (vr0 & 3)) * 8);

  const int rowqA = qblk * 64 + qsp * 32;
  const int rowqB = rowqA + 16;
  const short* qrowA = qm + (size_t)(rowqA + lo) * HEADD + s * 64;
  const short* qrowB = qm + (size_t)(rowqB + lo) * HEADD + s * 64;
  const short8 qA0 = *(const short8*)(qrowA + g * 8);
  const short8 qA1 = *(const short8*)(qrowA + 32 + g * 8);
  const short8 qB0 = *(const short8*)(qrowB + g * 8);
  const short8 qB1 = *(const short8*)(qrowB + 32 + g * 8);

  floatx4 accA[8], accB[8];
#pragma unroll
  for (int n = 0; n < 8; ++n) {
    accA[n] = floatx4{0.f, 0.f, 0.f, 0.f};
    accB[n] = floatx4{0.f, 0.f, 0.f, 0.f};
  }
  float lxA = 0.f, lxB = 0.f;

  const int kc0 = ((s * 8 + g) ^ (lo & 7)) * 8;
  const int kc1 = ((s * 8 + 4 + g) ^ (lo & 7)) * 8;
  const int kro0 = lo * 128, kro1 = (16 + lo) * 128;
  const int vco = (g ^ (lo & 3)) * 8;

  const int gA = (g & 1) * 2;
  const int idx0 = lo + 16 * gA, idx1 = idx0 + 16;
  const bool hi = (g >= 2);

  {
    int4 ka = *(const int4*)(kS + (size_t)(kv_base + kr0) * HEADD + kck * 8);
    int4 kbx = *(const int4*)(kS + (size_t)(kv_base + kr0 + 16) * HEADD + kck * 8);
    int4 va = *(const int4*)(vS + (size_t)vr0 * S_LEN + kv_base + vck * 8);
    int4 vb = *(const int4*)(vS + (size_t)(vr0 + 64) * S_LEN + kv_base + vck * 8);
    *(int4*)(&kt[0][kld0]) = ka;
    *(int4*)(&kt[0][kld1]) = kbx;
    *(int4*)(&vl[0][vld0]) = va;
    *(int4*)(&vl[0][vld1]) = vb;
  }
  __syncthreads();

  int cur = 0;
#pragma unroll 1
  for (int it = 0; it < 16; ++it) {
    int4 ka, kbx, va, vb;
    if (it + 1 < 16) {
      const int kvn = kv_base + (it + 1) * 32;
      ka  = *(const int4*)(kS + (size_t)(kvn + kr0) * HEADD + kck * 8);
      kbx = *(const int4*)(kS + (size_t)(kvn + kr0 + 16) * HEADD + kck * 8);
      va  = *(const int4*)(vS + (size_t)vr0 * S_LEN + kvn + vck * 8);
      vb  = *(const int4*)(vS + (size_t)(vr0 + 64) * S_LEN + kvn + vck * 8);
    }

    const short* kbase = &kt[cur][0];
    short8 a00 = *(const short8*)(kbase + kro0 + kc0);
    short8 a01 = *(const short8*)(kbase + kro0 + kc1);
    short8 a10 = *(const short8*)(kbase + kro1 + kc0);
    short8 a11 = *(const short8*)(kbase + kro1 + kc1);

    floatx4 z = floatx4{0.f, 0.f, 0.f, 0.f};
    floatx4 u;
    u = __builtin_amdgcn_mfma_f32_16x16x32_bf16(a00, qA0, z, 0, 0, 0);
    floatx4 T0A = __builtin_amdgcn_mfma_f32_16x16x32_bf16(a01, qA1, u, 0, 0, 0);
    u = __builtin_amdgcn_mfma_f32_16x16x32_bf16(a10, qA0, z, 0, 0, 0);
    floatx4 T1A = __builtin_amdgcn_mfma_f32_16x16x32_bf16(a11, qA1, u, 0, 0, 0);
    u = __builtin_amdgcn_mfma_f32_16x16x32_bf16(a00, qB0, z, 0, 0, 0);
    floatx4 T0B = __builtin_amdgcn_mfma_f32_16x16x32_bf16(a01, qB1, u, 0, 0, 0);
    u = __builtin_amdgcn_mfma_f32_16x16x32_bf16(a10, qB0, z, 0, 0, 0);
    floatx4 T1B = __builtin_amdgcn_mfma_f32_16x16x32_bf16(a11, qB1, u, 0, 0, 0);

    short8 paA, paB;
    {
      float p0 = fexp2(T0A[0]), p1 = fexp2(T0A[1]), p2 = fexp2(T0A[2]), p3 = fexp2(T0A[3]);
      float p4 = fexp2(T1A[0]), p5 = fexp2(T1A[1]), p6 = fexp2(T1A[2]), p7 = fexp2(T1A[3]);
      float lp = ((p0 + p1) + (p2 + p3)) + ((p4 + p5) + (p6 + p7));
      lp += __shfl_xor(lp, 16);
      lp += __shfl_xor(lp, 32);
      lxA += lp;
      int c00 = pkbf(p0, p1), c01 = pkbf(p2, p3);
      int c10 = pkbf(p4, p5), c11 = pkbf(p6, p7);
      int t0a = __shfl(c00, idx0), t0b = __shfl(c01, idx0);
      int t0c = __shfl(c00, idx1), t0d = __shfl(c01, idx1);
      int t1a = __shfl(c10, idx0), t1b = __shfl(c11, idx0);
      int t1c = __shfl(c10, idx1), t1d = __shfl(c11, idx1);
      int w0 = hi ? t1a : t0a, w1 = hi ? t1b : t0b;
      int w2 = hi ? t1c : t0c, w3 = hi ? t1d : t0d;
      int4 tmp = {w0, w1, w2, w3}; __builtin_memcpy(&paA, &tmp, 16);
    }
    {
      float p0 = fexp2(T0B[0]), p1 = fexp2(T0B[1]), p2 = fexp2(T0B[2]), p3 = fexp2(T0B[3]);
      float p4 = fexp2(T1B[0]), p5 = fexp2(T1B[1]), p6 = fexp2(T1B[2]), p7 = fexp2(T1B[3]);
      float lp = ((p0 + p1) + (p2 + p3)) + ((p4 + p5) + (p6 + p7));
      lp += __shfl_xor(lp, 16);
      lp += __shfl_xor(lp, 32);
      lxB += lp;
      int c00 = pkbf(p0, p1), c01 = pkbf(p2, p3);
      int c10 = pkbf(p4, p5), c11 = pkbf(p6, p7);
      int t0a = __shfl(c00, idx0), t0b = __shfl(c01, idx0);
      int t0c = __shfl(c00, idx1), t0d = __shfl(c01, idx1);
      int t1a = __shfl(c10, idx0), t1b = __shfl(c11, idx0);
      int t1c = __shfl(c10, idx1), t1d = __shfl(c11, idx1);
      int w0 = hi ? t1a : t0a, w1 = hi ? t1b : t0b;
      int w2 = hi ? t1c : t0c, w3 = hi ? t1d : t0d;
      int4 tmp = {w0, w1, w2, w3}; __builtin_memcpy(&paB, &tmp, 16);
    }

    const short* vbase = &vl[cur][0];
#pragma unroll
    for (int n = 0; n < 8; ++n) {
      short8 vf = *(const short8*)(vbase + (n * 16 + lo) * 32 + vco);
      accA[n] = __builtin_amdgcn_mfma_f32_16x16x32_bf16(paA, vf, accA[n], 0, 0, 0);
      accB[n] = __builtin_amdgcn_mfma_f32_16x16x32_bf16(paB, vf, accB[n], 0, 0, 0);
    }

    if (it + 1 < 16) {
      *(int4*)(&kt[cur ^ 1][kld0]) = ka;
      *(int4*)(&kt[cur ^ 1][kld1]) = kbx;
      *(int4*)(&vl[cur ^ 1][vld0]) = va;
      *(int4*)(&vl[cur ^ 1][vld1]) = vb;
    }
    __syncthreads();
    cur ^= 1;
  }

  short* pw = po + ((size_t)(ksp * 2 + s) * 8192) * 128;
#pragma unroll
  for (int j = 0; j < 4; ++j) {
    short8 pk;
#pragma unroll
    for (int n = 0; n < 8; ++n) pk[n] = f2bs(accA[n][j]);
    *(short8*)(pw + (size_t)(rowqA + g * 4 + j) * 128 + lo * 8) = pk;
#pragma unroll
    for (int n = 0; n < 8; ++n) pk[n] = f2bs(accB[n][j]);
    *(short8*)(pw + (size_t)(rowqB + g * 4 + j) * 128 + lo * 8) = pk;
  }
  if (g == 0) {
    pls[(size_t)(ksp * 2 + s) * 8192 + rowqA + lo] = lxA;
    pls[(size_t)(ksp * 2 + s) * 8192 + rowqB + lo] = lxB;
  }
}

// ---- Kernel 4: merge 8 ksp partials + diff combine + RMSNorm -> out (unchanged)
__global__ __launch_bounds__(256) void merge_kernel(const short* __restrict__ po,
                                                    const float* __restrict__ pls,
                                                    const float* __restrict__ lq1,
                                                    const float* __restrict__ lq2,
                                                    const float* __restrict__ lk1,
                                                    const float* __restrict__ lk2,
                                                    const float* __restrict__ rmsw,
                                                    float* __restrict__ out) {
  const int tid = threadIdx.x;
  const int row = blockIdx.x * 16 + (tid >> 4);
  const int lo = tid & 15;

  float a1s = 0.f, a2s = 0.f;
  for (int i = 0; i < 64; ++i) {
    a1s = fmaf(lq1[i], lk1[i], a1s);
    a2s = fmaf(lq2[i], lk2[i], a2s);
  }
  const float lam = __expf(a1s) - __expf(a2s) + 0.7836057665316245f;

  float o1[8], o2[8];
#pragma unroll
  for (int n = 0; n < 8; ++n) { o1[n] = 0.f; o2[n] = 0.f; }
  float l1 = 0.f, l2 = 0.f;
#pragma unroll
  for (int ksp = 0; ksp < 8; ++ksp) {
    short8 sa = *(const short8*)(po + ((size_t)(ksp * 2 + 0) * 8192 + row) * 128 + lo * 8);
    short8 sb = *(const short8*)(po + ((size_t)(ksp * 2 + 1) * 8192 + row) * 128 + lo * 8);
#pragma unroll
    for (int n = 0; n < 8; ++n) { o1[n] += bs2f(sa[n]); o2[n] += bs2f(sb[n]); }
    l1 += pls[(size_t)(ksp * 2 + 0) * 8192 + row];
    l2 += pls[(size_t)(ksp * 2 + 1) * 8192 + row];
  }
  const float iL1 = 1.f / l1, iL2 = 1.f / l2;

  float v[8];
  float ssq = 0.f;
#pragma unroll
  for (int n = 0; n < 8; ++n) {
    v[n] = o1[n] * iL1 - lam * (o2[n] * iL2);
    ssq += v[n] * v[n];
  }
  ssq += __shfl_xor(ssq, 1);
  ssq += __shfl_xor(ssq, 2);
  ssq += __shfl_xor(ssq, 4);
  ssq += __shfl_xor(ssq, 8);
  const float rr = rsqrtf(ssq * (1.f / 128.f) + 1.1920928955078125e-07f);

  float* ob = out + (size_t)row * 128;
#pragma unroll
  for (int n = 0; n < 8; ++n) {
    int c = n * 16 + lo;
    ob[c] = 0.21639423346837554f * v[n] * rr * rmsw[c];
  }
}

extern "C" void kernel_launch(void* const* d_in, const int* in_sizes, int n_in,
                              void* d_out, int out_size, void* d_ws, size_t ws_size,
                              hipStream_t stream) {
  const float* x   = (const float*)d_in[0];
  const float* wq  = (const float*)d_in[1];
  const float* wk  = (const float*)d_in[2];
  const float* wv  = (const float*)d_in[3];
  const float* lq1 = (const float*)d_in[4];
  const float* lq2 = (const float*)d_in[5];
  const float* lk1 = (const float*)d_in[6];
  const float* lk2 = (const float*)d_in[7];
  const float* rw  = (const float*)d_in[8];
  float* out = (float*)d_out;

  char* ws = (char*)d_ws;
  short* qm  = (short*)(ws);                        // 2 MB (q pre-scaled 0.125*log2e)
  short* kb  = (short*)(ws + (2u << 20));           // 2 MB
  short* vt  = (short*)(ws + (4u << 20));           // 2 MB (V^T [b][h][s])
  short* wc  = (short*)(ws + (6u << 20));           // 1.5 MB
  short* vstage = (short*)(ws + (6u << 20) + 1572864u); // 2 MB [8192][128]
  short* po  = (short*)(ws + (8u << 20));           // 32 MB [16][8192][128]
  float* pls = (float*)(ws + (40u << 20));          // 512 KB fp32 [16][8192]

  convw_kernel<<<768, 256, 0, stream>>>(wq, wk, wv, wc);
  proj_kernel<<<512, 256, 0, stream>>>(x, wc, qm, kb, vstage);
  conv_v_kernel<<<128, 256, 0, stream>>>(vstage, vt);
  attn_kernel<<<1024, 256, 0, stream>>>(qm, kb, vt, po, pls);
  merge_kernel<<<512, 256, 0, stream>>>(po, pls, lq1, lq2, lk1, lk2, rw, out);
}

// Round 23
// 92.734 us; speedup vs baseline: 1.1211x; 1.0421x over previous
//
#include <hip/hip_runtime.h>
#include <hip/hip_bf16.h>
#include <math.h>

#define S_LEN 4096
#define DMODEL 2048
#define HEADD 128

typedef __attribute__((ext_vector_type(8))) short short8;
typedef __attribute__((ext_vector_type(4))) float floatx4;

__device__ __forceinline__ short f2bs(float f) {
  __hip_bfloat16 h = __float2bfloat16(f);
  short s; __builtin_memcpy(&s, &h, 2); return s;
}
__device__ __forceinline__ float bs2f(short s) {
  unsigned u = ((unsigned)(unsigned short)s) << 16;
  float f; __builtin_memcpy(&f, &u, 4); return f;
}
__device__ __forceinline__ int pkbf(float a, float b) {  // (lo=a, hi=b) bf16 pair
  return (int)(((unsigned)(unsigned short)f2bs(b) << 16) |
               (unsigned)(unsigned short)f2bs(a));
}
// raw v_exp_f32: 2^x, no libm guard code (R21/R22 lesson)
__device__ __forceinline__ float fexp2(float x) { return __builtin_amdgcn_exp2f(x); }

// ---- Kernel 1: convert Wq,Wk,Wv (fp32 [128][2048] each) -> wc bf16 [384][2048]
__global__ __launch_bounds__(256) void convw_kernel(const float* __restrict__ wq,
                                                    const float* __restrict__ wk,
                                                    const float* __restrict__ wv,
                                                    short* __restrict__ wc) {
  const int per = 128 * 2048;
  int e = (blockIdx.x * blockDim.x + threadIdx.x) * 4;
  const float* src = (e < per) ? wq : (e < 2 * per) ? wk : wv;
  int off = e & (per - 1);
  float4 v = *(const float4*)(src + off);
  short4 r;
  r.x = f2bs(v.x); r.y = f2bs(v.y); r.z = f2bs(v.z); r.w = f2bs(v.w);
  *(short4*)(wc + e) = r;
}

// ---- Kernel 2: projection GEMM (unchanged; q pre-scale includes log2(e))
__global__ __launch_bounds__(256, 3) void proj_kernel(const float* __restrict__ x,
                                                      const short* __restrict__ wc,
                                                      short* __restrict__ qm,
                                                      short* __restrict__ kb,
                                                      short* __restrict__ vstage) {
  const int tid = threadIdx.x;
  const int w = tid >> 6;
  const int lane = tid & 63;
  const int lo = lane & 15, g = lane >> 4;
  const int id = blockIdx.x;
  const int nq = id >> 7, mb = id & 127;
  const int m0 = mb * 64;
  const int n0 = nq * 96;

  __shared__ short xt[2][64 * 64];
  __shared__ short wt[2][96 * 64];

  const int r8 = tid >> 3, sc = tid & 7;
  const float* xs0 = x + (size_t)(m0 + r8) * DMODEL + sc * 8;
  const float* xs1 = x + (size_t)(m0 + 32 + r8) * DMODEL + sc * 8;
  const short* ws0 = wc + (size_t)(n0 + r8) * DMODEL + sc * 8;
  const short* ws1 = wc + (size_t)(n0 + 32 + r8) * DMODEL + sc * 8;
  const short* ws2 = wc + (size_t)(n0 + 64 + r8) * DMODEL + sc * 8;
  const int xl0 = r8 * 64 + ((sc ^ (r8 & 7)) * 8);
  const int xl1 = (32 + r8) * 64 + ((sc ^ (r8 & 7)) * 8);
  const int wlo0 = r8 * 64 + ((sc ^ (r8 & 7)) * 8);
  const int wlo1 = (32 + r8) * 64 + ((sc ^ (r8 & 7)) * 8);
  const int wlo2 = (64 + r8) * 64 + ((sc ^ (r8 & 7)) * 8);

  const int mrow = (w >> 1) * 32;
  const int ncol = (w & 1) * 48;
  int aoff[2][2], boff[3][2];
#pragma unroll
  for (int mi = 0; mi < 2; ++mi) {
    int r = mrow + mi * 16 + lo;
#pragma unroll
    for (int kc = 0; kc < 2; ++kc)
      aoff[mi][kc] = r * 64 + (((kc * 4 + g) ^ (r & 7)) * 8);
  }
#pragma unroll
  for (int t = 0; t < 3; ++t) {
    int r = ncol + t * 16 + lo;
#pragma unroll
    for (int kc = 0; kc < 2; ++kc)
      boff[t][kc] = r * 64 + (((kc * 4 + g) ^ (r & 7)) * 8);
  }

  floatx4 acc[2][3];
#pragma unroll
  for (int mi = 0; mi < 2; ++mi)
#pragma unroll
    for (int t = 0; t < 3; ++t) acc[mi][t] = floatx4{0.f, 0.f, 0.f, 0.f};

  {
    float4 a0 = *(const float4*)(xs0), a1 = *(const float4*)(xs0 + 4);
    float4 b0 = *(const float4*)(xs1), b1 = *(const float4*)(xs1 + 4);
    int4 w0 = *(const int4*)(ws0);
    int4 w1 = *(const int4*)(ws1);
    int4 w2 = *(const int4*)(ws2);
    short8 sA, sB;
    sA[0]=f2bs(a0.x); sA[1]=f2bs(a0.y); sA[2]=f2bs(a0.z); sA[3]=f2bs(a0.w);
    sA[4]=f2bs(a1.x); sA[5]=f2bs(a1.y); sA[6]=f2bs(a1.z); sA[7]=f2bs(a1.w);
    sB[0]=f2bs(b0.x); sB[1]=f2bs(b0.y); sB[2]=f2bs(b0.z); sB[3]=f2bs(b0.w);
    sB[4]=f2bs(b1.x); sB[5]=f2bs(b1.y); sB[6]=f2bs(b1.z); sB[7]=f2bs(b1.w);
    *(short8*)&xt[0][xl0] = sA;
    *(short8*)&xt[0][xl1] = sB;
    *(int4*)&wt[0][wlo0] = w0;
    *(int4*)&wt[0][wlo1] = w1;
    *(int4*)&wt[0][wlo2] = w2;
  }
  __syncthreads();

  int cur = 0;
#pragma unroll 1
  for (int it = 0; it < 32; ++it) {
    float4 a0, a1, b0, b1;
    int4 w0, w1, w2;
    if (it + 1 < 32) {
      const int k = (it + 1) * 64;
      a0 = *(const float4*)(xs0 + k); a1 = *(const float4*)(xs0 + k + 4);
      b0 = *(const float4*)(xs1 + k); b1 = *(const float4*)(xs1 + k + 4);
      w0 = *(const int4*)(ws0 + k);
      w1 = *(const int4*)(ws1 + k);
      w2 = *(const int4*)(ws2 + k);
    }

    {
      const short* xb = &xt[cur][0];
      const short* wb = &wt[cur][0];
      short8 af[2][2], bf[3][2];
#pragma unroll
      for (int mi = 0; mi < 2; ++mi)
#pragma unroll
        for (int kc = 0; kc < 2; ++kc) af[mi][kc] = *(const short8*)(xb + aoff[mi][kc]);
#pragma unroll
      for (int t = 0; t < 3; ++t)
#pragma unroll
        for (int kc = 0; kc < 2; ++kc) bf[t][kc] = *(const short8*)(wb + boff[t][kc]);
#pragma unroll
      for (int kc = 0; kc < 2; ++kc)
#pragma unroll
        for (int mi = 0; mi < 2; ++mi)
#pragma unroll
          for (int t = 0; t < 3; ++t)
            acc[mi][t] = __builtin_amdgcn_mfma_f32_16x16x32_bf16(af[mi][kc], bf[t][kc], acc[mi][t], 0, 0, 0);
    }

    if (it + 1 < 32) {
      short8 sA, sB;
      sA[0]=f2bs(a0.x); sA[1]=f2bs(a0.y); sA[2]=f2bs(a0.z); sA[3]=f2bs(a0.w);
      sA[4]=f2bs(a1.x); sA[5]=f2bs(a1.y); sA[6]=f2bs(a1.z); sA[7]=f2bs(a1.w);
      sB[0]=f2bs(b0.x); sB[1]=f2bs(b0.y); sB[2]=f2bs(b0.z); sB[3]=f2bs(b0.w);
      sB[4]=f2bs(b1.x); sB[5]=f2bs(b1.y); sB[6]=f2bs(b1.z); sB[7]=f2bs(b1.w);
      *(short8*)&xt[cur ^ 1][xl0] = sA;
      *(short8*)&xt[cur ^ 1][xl1] = sB;
      *(int4*)&wt[cur ^ 1][wlo0] = w0;
      *(int4*)&wt[cur ^ 1][wlo1] = w1;
      *(int4*)&wt[cur ^ 1][wlo2] = w2;
    }
    __syncthreads();
    cur ^= 1;
  }

#pragma unroll
  for (int t = 0; t < 3; ++t) {
    int n = n0 + ncol + t * 16 + lo;
#pragma unroll
    for (int mi = 0; mi < 2; ++mi)
#pragma unroll
      for (int j = 0; j < 4; ++j) {
        int m = m0 + mrow + mi * 16 + g * 4 + j;
        float v = acc[mi][t][j];
        if (n < HEADD) {
          qm[(size_t)m * HEADD + n] = f2bs(v * 0.18033688011112042f);  // 0.125*log2e
        } else if (n < 2 * HEADD) {
          kb[(size_t)m * HEADD + (n - HEADD)] = f2bs(v);
        } else {
          vstage[(size_t)m * HEADD + (n - 2 * HEADD)] = f2bs(v);
        }
      }
  }
}

// ---- Kernel 2c: vstage[8192][128] -> vt[b][h][s'] via LDS transpose,
// with kv-PERMUTED s' within each 32-block:
//   perm(t<16)  = (t>>2)*8 + (t&3)
//   perm(t>=16) = ((t-16)>>2)*8 + 4 + ((t-16)&3)
// chosen so attn's P fragments need ZERO cross-lane transpose (P lane-local).
// Applied on the READ side (gather): writes stay coalesced.
__global__ __launch_bounds__(256) void conv_v_kernel(const short* __restrict__ vstage,
                                                     short* __restrict__ vt) {
  const int tid = threadIdx.x;
  const int bb = blockIdx.x >> 6, st = blockIdx.x & 63;
  const int s0 = st * 64;

  __shared__ short ld[64][136];

  const int r = tid >> 2, c8 = (tid & 3) * 32;
#pragma unroll
  for (int q = 0; q < 4; ++q) {
    const size_t off = (size_t)(bb * 4096 + s0 + r) * 128 + c8 + q * 8;
    *(short8*)(&ld[r][c8 + q * 8]) = *(const short8*)(vstage + off);
  }
  __syncthreads();

  const int h = tid >> 1, sh = (tid & 1) * 32;
#pragma unroll
  for (int q = 0; q < 4; ++q) {
    short8 t;
#pragma unroll
    for (int i = 0; i < 8; ++i) {
      // dest low-5 = 8q+i; source = perm^-1(8q+i)
      int src5 = (i < 4) ? (4 * q + i) : (16 + 4 * q + (i - 4));
      t[i] = ld[sh + src5][h];
    }
    *(short8*)(vt + ((size_t)bb * 128 + h) * 4096 + s0 + sh + q * 8) = t;
  }
}

// ---- Kernel 3: LDS-staged flash attention. kv-permuted V (conv_v) makes the
// P->A-frag hand-off LANE-LOCAL: pa = {pk(p0,p1),pk(p2,p3),pk(p4,p5),pk(p6,p7)}
// directly -- the 16 ds_bpermute + 8 cndmask per wave-iter are GONE.
__global__ __launch_bounds__(256, 3) void attn_kernel(const short* __restrict__ qm,
                                                      const short* __restrict__ kb,
                                                      const short* __restrict__ vt,
                                                      short* __restrict__ po,
                                                      float* __restrict__ pls) {
  const int tid = threadIdx.x;
  const int w = tid >> 6;
  const int lane = tid & 63;
  const int lo = lane & 15, g = lane >> 4;
  const int qsp = w >> 1;
  const int s = w & 1;
  const int id = blockIdx.x;
  const int ksp = id & 7;
  const int qblk = id >> 3;
  const int b = qblk >> 6;
  const int kv_base = ksp * 512;

  __shared__ short kt[2][32 * 128];
  __shared__ short vl[2][128 * 32];

  const int kr0 = tid >> 4, kck = tid & 15;
  const int vr0 = tid >> 2, vck = tid & 3;
  const short* kS = kb + (size_t)b * S_LEN * HEADD;
  const short* vS = vt + (size_t)b * HEADD * S_LEN;
  const int kld0 = kr0 * 128 + ((kck ^ (kr0 & 7)) * 8);
  const int kld1 = (kr0 + 16) * 128 + ((kck ^ (kr0 & 7)) * 8);
  const int vld0 = vr0 * 32 + ((vck ^ (vr0 & 3)) * 8);
  const int vld1 = (vr0 + 64) * 32 + ((vck ^ (vr0 & 3)) * 8);

  const int rowqA = qblk * 64 + qsp * 32;
  const int rowqB = rowqA + 16;
  const short* qrowA = qm + (size_t)(rowqA + lo) * HEADD + s * 64;
  const short* qrowB = qm + (size_t)(rowqB + lo) * HEADD + s * 64;
  const short8 qA0 = *(const short8*)(qrowA + g * 8);
  const short8 qA1 = *(const short8*)(qrowA + 32 + g * 8);
  const short8 qB0 = *(const short8*)(qrowB + g * 8);
  const short8 qB1 = *(const short8*)(qrowB + 32 + g * 8);

  floatx4 accA[8], accB[8];
#pragma unroll
  for (int n = 0; n < 8; ++n) {
    accA[n] = floatx4{0.f, 0.f, 0.f, 0.f};
    accB[n] = floatx4{0.f, 0.f, 0.f, 0.f};
  }
  float lxA = 0.f, lxB = 0.f;

  const int kc0 = ((s * 8 + g) ^ (lo & 7)) * 8;
  const int kc1 = ((s * 8 + 4 + g) ^ (lo & 7)) * 8;
  const int kro0 = lo * 128, kro1 = (16 + lo) * 128;
  const int vco = (g ^ (lo & 3)) * 8;

  {
    int4 ka = *(const int4*)(kS + (size_t)(kv_base + kr0) * HEADD + kck * 8);
    int4 kbx = *(const int4*)(kS + (size_t)(kv_base + kr0 + 16) * HEADD + kck * 8);
    int4 va = *(const int4*)(vS + (size_t)vr0 * S_LEN + kv_base + vck * 8);
    int4 vb = *(const int4*)(vS + (size_t)(vr0 + 64) * S_LEN + kv_base + vck * 8);
    *(int4*)(&kt[0][kld0]) = ka;
    *(int4*)(&kt[0][kld1]) = kbx;
    *(int4*)(&vl[0][vld0]) = va;
    *(int4*)(&vl[0][vld1]) = vb;
  }
  __syncthreads();

  int cur = 0;
#pragma unroll 1
  for (int it = 0; it < 16; ++it) {
    int4 ka, kbx, va, vb;
    if (it + 1 < 16) {
      const int kvn = kv_base + (it + 1) * 32;
      ka  = *(const int4*)(kS + (size_t)(kvn + kr0) * HEADD + kck * 8);
      kbx = *(const int4*)(kS + (size_t)(kvn + kr0 + 16) * HEADD + kck * 8);
      va  = *(const int4*)(vS + (size_t)vr0 * S_LEN + kvn + vck * 8);
      vb  = *(const int4*)(vS + (size_t)(vr0 + 64) * S_LEN + kvn + vck * 8);
    }

    const short* kbase = &kt[cur][0];
    short8 a00 = *(const short8*)(kbase + kro0 + kc0);
    short8 a01 = *(const short8*)(kbase + kro0 + kc1);
    short8 a10 = *(const short8*)(kbase + kro1 + kc0);
    short8 a11 = *(const short8*)(kbase + kro1 + kc1);

    floatx4 z = floatx4{0.f, 0.f, 0.f, 0.f};
    floatx4 u;
    u = __builtin_amdgcn_mfma_f32_16x16x32_bf16(a00, qA0, z, 0, 0, 0);
    floatx4 T0A = __builtin_amdgcn_mfma_f32_16x16x32_bf16(a01, qA1, u, 0, 0, 0);
    u = __builtin_amdgcn_mfma_f32_16x16x32_bf16(a10, qA0, z, 0, 0, 0);
    floatx4 T1A = __builtin_amdgcn_mfma_f32_16x16x32_bf16(a11, qA1, u, 0, 0, 0);
    u = __builtin_amdgcn_mfma_f32_16x16x32_bf16(a00, qB0, z, 0, 0, 0);
    floatx4 T0B = __builtin_amdgcn_mfma_f32_16x16x32_bf16(a01, qB1, u, 0, 0, 0);
    u = __builtin_amdgcn_mfma_f32_16x16x32_bf16(a10, qB0, z, 0, 0, 0);
    floatx4 T1B = __builtin_amdgcn_mfma_f32_16x16x32_bf16(a11, qB1, u, 0, 0, 0);

    short8 paA, paB;
    {
      float p0 = fexp2(T0A[0]), p1 = fexp2(T0A[1]), p2 = fexp2(T0A[2]), p3 = fexp2(T0A[3]);
      float p4 = fexp2(T1A[0]), p5 = fexp2(T1A[1]), p6 = fexp2(T1A[2]), p7 = fexp2(T1A[3]);
      float lp = ((p0 + p1) + (p2 + p3)) + ((p4 + p5) + (p6 + p7));
      lp += __shfl_xor(lp, 16);
      lp += __shfl_xor(lp, 32);
      lxA += lp;
      int4 tmp = {pkbf(p0, p1), pkbf(p2, p3), pkbf(p4, p5), pkbf(p6, p7)};
      __builtin_memcpy(&paA, &tmp, 16);
    }
    {
      float p0 = fexp2(T0B[0]), p1 = fexp2(T0B[1]), p2 = fexp2(T0B[2]), p3 = fexp2(T0B[3]);
      float p4 = fexp2(T1B[0]), p5 = fexp2(T1B[1]), p6 = fexp2(T1B[2]), p7 = fexp2(T1B[3]);
      float lp = ((p0 + p1) + (p2 + p3)) + ((p4 + p5) + (p6 + p7));
      lp += __shfl_xor(lp, 16);
      lp += __shfl_xor(lp, 32);
      lxB += lp;
      int4 tmp = {pkbf(p0, p1), pkbf(p2, p3), pkbf(p4, p5), pkbf(p6, p7)};
      __builtin_memcpy(&paB, &tmp, 16);
    }

    const short* vbase = &vl[cur][0];
#pragma unroll
    for (int n = 0; n < 8; ++n) {
      short8 vf = *(const short8*)(vbase + (n * 16 + lo) * 32 + vco);
      accA[n] = __builtin_amdgcn_mfma_f32_16x16x32_bf16(paA, vf, accA[n], 0, 0, 0);
      accB[n] = __builtin_amdgcn_mfma_f32_16x16x32_bf16(paB, vf, accB[n], 0, 0, 0);
    }

    if (it + 1 < 16) {
      *(int4*)(&kt[cur ^ 1][kld0]) = ka;
      *(int4*)(&kt[cur ^ 1][kld1]) = kbx;
      *(int4*)(&vl[cur ^ 1][vld0]) = va;
      *(int4*)(&vl[cur ^ 1][vld1]) = vb;
    }
    __syncthreads();
    cur ^= 1;
  }

  short* pw = po + ((size_t)(ksp * 2 + s) * 8192) * 128;
#pragma unroll
  for (int j = 0; j < 4; ++j) {
    short8 pk;
#pragma unroll
    for (int n = 0; n < 8; ++n) pk[n] = f2bs(accA[n][j]);
    *(short8*)(pw + (size_t)(rowqA + g * 4 + j) * 128 + lo * 8) = pk;
#pragma unroll
    for (int n = 0; n < 8; ++n) pk[n] = f2bs(accB[n][j]);
    *(short8*)(pw + (size_t)(rowqB + g * 4 + j) * 128 + lo * 8) = pk;
  }
  if (g == 0) {
    pls[(size_t)(ksp * 2 + s) * 8192 + rowqA + lo] = lxA;
    pls[(size_t)(ksp * 2 + s) * 8192 + rowqB + lo] = lxB;
  }
}

// ---- Kernel 4: merge 8 ksp partials + diff combine + RMSNorm -> out (unchanged)
__global__ __launch_bounds__(256) void merge_kernel(const short* __restrict__ po,
                                                    const float* __restrict__ pls,
                                                    const float* __restrict__ lq1,
                                                    const float* __restrict__ lq2,
                                                    const float* __restrict__ lk1,
                                                    const float* __restrict__ lk2,
                                                    const float* __restrict__ rmsw,
                                                    float* __restrict__ out) {
  const int tid = threadIdx.x;
  const int row = blockIdx.x * 16 + (tid >> 4);
  const int lo = tid & 15;

  float a1s = 0.f, a2s = 0.f;
  for (int i = 0; i < 64; ++i) {
    a1s = fmaf(lq1[i], lk1[i], a1s);
    a2s = fmaf(lq2[i], lk2[i], a2s);
  }
  const float lam = __expf(a1s) - __expf(a2s) + 0.7836057665316245f;

  float o1[8], o2[8];
#pragma unroll
  for (int n = 0; n < 8; ++n) { o1[n] = 0.f; o2[n] = 0.f; }
  float l1 = 0.f, l2 = 0.f;
#pragma unroll
  for (int ksp = 0; ksp < 8; ++ksp) {
    short8 sa = *(const short8*)(po + ((size_t)(ksp * 2 + 0) * 8192 + row) * 128 + lo * 8);
    short8 sb = *(const short8*)(po + ((size_t)(ksp * 2 + 1) * 8192 + row) * 128 + lo * 8);
#pragma unroll
    for (int n = 0; n < 8; ++n) { o1[n] += bs2f(sa[n]); o2[n] += bs2f(sb[n]); }
    l1 += pls[(size_t)(ksp * 2 + 0) * 8192 + row];
    l2 += pls[(size_t)(ksp * 2 + 1) * 8192 + row];
  }
  const float iL1 = 1.f / l1, iL2 = 1.f / l2;

  float v[8];
  float ssq = 0.f;
#pragma unroll
  for (int n = 0; n < 8; ++n) {
    v[n] = o1[n] * iL1 - lam * (o2[n] * iL2);
    ssq += v[n] * v[n];
  }
  ssq += __shfl_xor(ssq, 1);
  ssq += __shfl_xor(ssq, 2);
  ssq += __shfl_xor(ssq, 4);
  ssq += __shfl_xor(ssq, 8);
  const float rr = rsqrtf(ssq * (1.f / 128.f) + 1.1920928955078125e-07f);

  float* ob = out + (size_t)row * 128;
#pragma unroll
  for (int n = 0; n < 8; ++n) {
    int c = n * 16 + lo;
    ob[c] = 0.21639423346837554f * v[n] * rr * rmsw[c];
  }
}

extern "C" void kernel_launch(void* const* d_in, const int* in_sizes, int n_in,
                              void* d_out, int out_size, void* d_ws, size_t ws_size,
                              hipStream_t stream) {
  const float* x   = (const float*)d_in[0];
  const float* wq  = (const float*)d_in[1];
  const float* wk  = (const float*)d_in[2];
  const float* wv  = (const float*)d_in[3];
  const float* lq1 = (const float*)d_in[4];
  const float* lq2 = (const float*)d_in[5];
  const float* lk1 = (const float*)d_in[6];
  const float* lk2 = (const float*)d_in[7];
  const float* rw  = (const float*)d_in[8];
  float* out = (float*)d_out;

  char* ws = (char*)d_ws;
  short* qm  = (short*)(ws);                        // 2 MB (q pre-scaled 0.125*log2e)
  short* kb  = (short*)(ws + (2u << 20));           // 2 MB
  short* vt  = (short*)(ws + (4u << 20));           // 2 MB (V^T, kv-permuted per 32)
  short* wc  = (short*)(ws + (6u << 20));           // 1.5 MB
  short* vstage = (short*)(ws + (6u << 20) + 1572864u); // 2 MB [8192][128]
  short* po  = (short*)(ws + (8u << 20));           // 32 MB [16][8192][128]
  float* pls = (float*)(ws + (40u << 20));          // 512 KB fp32 [16][8192]

  convw_kernel<<<768, 256, 0, stream>>>(wq, wk, wv, wc);
  proj_kernel<<<512, 256, 0, stream>>>(x, wc, qm, kb, vstage);
  conv_v_kernel<<<128, 256, 0, stream>>>(vstage, vt);
  attn_kernel<<<1024, 256, 0, stream>>>(qm, kb, vt, po, pls);
  merge_kernel<<<512, 256, 0, stream>>>(po, pls, lq1, lq2, lk1, lk2, rw, out);
}

// Round 24
// 92.068 us; speedup vs baseline: 1.1292x; 1.0072x over previous
//
#include <hip/hip_runtime.h>
#include <hip/hip_bf16.h>
#include <math.h>

#define S_LEN 4096
#define DMODEL 2048
#define HEADD 128

typedef __attribute__((ext_vector_type(8))) short short8;
typedef __attribute__((ext_vector_type(4))) float floatx4;

__device__ __forceinline__ short f2bs(float f) {
  __hip_bfloat16 h = __float2bfloat16(f);
  short s; __builtin_memcpy(&s, &h, 2); return s;
}
__device__ __forceinline__ float bs2f(short s) {
  unsigned u = ((unsigned)(unsigned short)s) << 16;
  float f; __builtin_memcpy(&f, &u, 4); return f;
}
__device__ __forceinline__ int pkbf(float a, float b) {  // (lo=a, hi=b) bf16 pair
  return (int)(((unsigned)(unsigned short)f2bs(b) << 16) |
               (unsigned)(unsigned short)f2bs(a));
}
// raw v_exp_f32: 2^x, no libm guard code (R21/R22 lesson)
__device__ __forceinline__ float fexp2(float x) { return __builtin_amdgcn_exp2f(x); }

// ---- Kernel 1: convert Wq,Wk,Wv (fp32 [128][2048] each) -> wc bf16 [384][2048]
__global__ __launch_bounds__(256) void convw_kernel(const float* __restrict__ wq,
                                                    const float* __restrict__ wk,
                                                    const float* __restrict__ wv,
                                                    short* __restrict__ wc) {
  const int per = 128 * 2048;
  int e = (blockIdx.x * blockDim.x + threadIdx.x) * 4;
  const float* src = (e < per) ? wq : (e < 2 * per) ? wk : wv;
  int off = e & (per - 1);
  float4 v = *(const float4*)(src + off);
  short4 r;
  r.x = f2bs(v.x); r.y = f2bs(v.y); r.z = f2bs(v.z); r.w = f2bs(v.w);
  *(short4*)(wc + e) = r;
}

// ---- Kernel 2: projection GEMM, dense 64x96 tile + kh-SPLIT (k halves of
// 1024, 16 iters each). grid 1024 = 2kh x 4nq x 128mb -> 4 blocks/CU =
// 16 waves/CU (2x R23: occupancy was proj's binder -- 2 waves/SIMD left
// ~700cy/iter of HBM latency uncovered). bf16 partial stores to qa0/qa1.
__global__ __launch_bounds__(256, 3) void proj_kernel(const float* __restrict__ x,
                                                      const short* __restrict__ wc,
                                                      short* __restrict__ qa0,
                                                      short* __restrict__ qa1) {
  const int tid = threadIdx.x;
  const int w = tid >> 6;
  const int lane = tid & 63;
  const int lo = lane & 15, g = lane >> 4;
  const int id = blockIdx.x;
  const int kh = id >> 9, nq = (id >> 7) & 3, mb = id & 127;
  const int m0 = mb * 64;
  const int n0 = nq * 96;
  const int k0 = kh * 1024;
  short* qa = kh ? qa1 : qa0;

  __shared__ short xt[2][64 * 64];
  __shared__ short wt[2][96 * 64];

  const int r8 = tid >> 3, sc = tid & 7;
  const float* xs0 = x + (size_t)(m0 + r8) * DMODEL + k0 + sc * 8;
  const float* xs1 = x + (size_t)(m0 + 32 + r8) * DMODEL + k0 + sc * 8;
  const short* ws0 = wc + (size_t)(n0 + r8) * DMODEL + k0 + sc * 8;
  const short* ws1 = wc + (size_t)(n0 + 32 + r8) * DMODEL + k0 + sc * 8;
  const short* ws2 = wc + (size_t)(n0 + 64 + r8) * DMODEL + k0 + sc * 8;
  const int xl0 = r8 * 64 + ((sc ^ (r8 & 7)) * 8);
  const int xl1 = (32 + r8) * 64 + ((sc ^ (r8 & 7)) * 8);
  const int wlo0 = r8 * 64 + ((sc ^ (r8 & 7)) * 8);
  const int wlo1 = (32 + r8) * 64 + ((sc ^ (r8 & 7)) * 8);
  const int wlo2 = (64 + r8) * 64 + ((sc ^ (r8 & 7)) * 8);

  const int mrow = (w >> 1) * 32;
  const int ncol = (w & 1) * 48;
  int aoff[2][2], boff[3][2];
#pragma unroll
  for (int mi = 0; mi < 2; ++mi) {
    int r = mrow + mi * 16 + lo;
#pragma unroll
    for (int kc = 0; kc < 2; ++kc)
      aoff[mi][kc] = r * 64 + (((kc * 4 + g) ^ (r & 7)) * 8);
  }
#pragma unroll
  for (int t = 0; t < 3; ++t) {
    int r = ncol + t * 16 + lo;
#pragma unroll
    for (int kc = 0; kc < 2; ++kc)
      boff[t][kc] = r * 64 + (((kc * 4 + g) ^ (r & 7)) * 8);
  }

  floatx4 acc[2][3];
#pragma unroll
  for (int mi = 0; mi < 2; ++mi)
#pragma unroll
    for (int t = 0; t < 3; ++t) acc[mi][t] = floatx4{0.f, 0.f, 0.f, 0.f};

  {
    float4 a0 = *(const float4*)(xs0), a1 = *(const float4*)(xs0 + 4);
    float4 b0 = *(const float4*)(xs1), b1 = *(const float4*)(xs1 + 4);
    int4 w0 = *(const int4*)(ws0);
    int4 w1 = *(const int4*)(ws1);
    int4 w2 = *(const int4*)(ws2);
    short8 sA, sB;
    sA[0]=f2bs(a0.x); sA[1]=f2bs(a0.y); sA[2]=f2bs(a0.z); sA[3]=f2bs(a0.w);
    sA[4]=f2bs(a1.x); sA[5]=f2bs(a1.y); sA[6]=f2bs(a1.z); sA[7]=f2bs(a1.w);
    sB[0]=f2bs(b0.x); sB[1]=f2bs(b0.y); sB[2]=f2bs(b0.z); sB[3]=f2bs(b0.w);
    sB[4]=f2bs(b1.x); sB[5]=f2bs(b1.y); sB[6]=f2bs(b1.z); sB[7]=f2bs(b1.w);
    *(short8*)&xt[0][xl0] = sA;
    *(short8*)&xt[0][xl1] = sB;
    *(int4*)&wt[0][wlo0] = w0;
    *(int4*)&wt[0][wlo1] = w1;
    *(int4*)&wt[0][wlo2] = w2;
  }
  __syncthreads();

  int cur = 0;
#pragma unroll 1
  for (int it = 0; it < 16; ++it) {
    float4 a0, a1, b0, b1;
    int4 w0, w1, w2;
    if (it + 1 < 16) {
      const int k = (it + 1) * 64;
      a0 = *(const float4*)(xs0 + k); a1 = *(const float4*)(xs0 + k + 4);
      b0 = *(const float4*)(xs1 + k); b1 = *(const float4*)(xs1 + k + 4);
      w0 = *(const int4*)(ws0 + k);
      w1 = *(const int4*)(ws1 + k);
      w2 = *(const int4*)(ws2 + k);
    }

    {
      const short* xb = &xt[cur][0];
      const short* wb = &wt[cur][0];
      short8 af[2][2], bf[3][2];
#pragma unroll
      for (int mi = 0; mi < 2; ++mi)
#pragma unroll
        for (int kc = 0; kc < 2; ++kc) af[mi][kc] = *(const short8*)(xb + aoff[mi][kc]);
#pragma unroll
      for (int t = 0; t < 3; ++t)
#pragma unroll
        for (int kc = 0; kc < 2; ++kc) bf[t][kc] = *(const short8*)(wb + boff[t][kc]);
#pragma unroll
      for (int kc = 0; kc < 2; ++kc)
#pragma unroll
        for (int mi = 0; mi < 2; ++mi)
#pragma unroll
          for (int t = 0; t < 3; ++t)
            acc[mi][t] = __builtin_amdgcn_mfma_f32_16x16x32_bf16(af[mi][kc], bf[t][kc], acc[mi][t], 0, 0, 0);
    }

    if (it + 1 < 16) {
      short8 sA, sB;
      sA[0]=f2bs(a0.x); sA[1]=f2bs(a0.y); sA[2]=f2bs(a0.z); sA[3]=f2bs(a0.w);
      sA[4]=f2bs(a1.x); sA[5]=f2bs(a1.y); sA[6]=f2bs(a1.z); sA[7]=f2bs(a1.w);
      sB[0]=f2bs(b0.x); sB[1]=f2bs(b0.y); sB[2]=f2bs(b0.z); sB[3]=f2bs(b0.w);
      sB[4]=f2bs(b1.x); sB[5]=f2bs(b1.y); sB[6]=f2bs(b1.z); sB[7]=f2bs(b1.w);
      *(short8*)&xt[cur ^ 1][xl0] = sA;
      *(short8*)&xt[cur ^ 1][xl1] = sB;
      *(int4*)&wt[cur ^ 1][wlo0] = w0;
      *(int4*)&wt[cur ^ 1][wlo1] = w1;
      *(int4*)&wt[cur ^ 1][wlo2] = w2;
    }
    __syncthreads();
    cur ^= 1;
  }

  // bf16 partial stores (merged in conv_qk / conv_v)
#pragma unroll
  for (int t = 0; t < 3; ++t) {
    int n = n0 + ncol + t * 16 + lo;
#pragma unroll
    for (int mi = 0; mi < 2; ++mi)
#pragma unroll
      for (int j = 0; j < 4; ++j) {
        int m = m0 + mrow + mi * 16 + g * 4 + j;
        qa[(size_t)m * 384 + n] = f2bs(acc[mi][t][j]);
      }
  }
}

// ---- Kernel 2b: qa0+qa1 cols 0..255 -> qm (scaled 0.125*log2e), kb
__global__ __launch_bounds__(256) void conv_qk_kernel(const short* __restrict__ qa0,
                                                      const short* __restrict__ qa1,
                                                      short* __restrict__ qm,
                                                      short* __restrict__ kb) {
  int e = (blockIdx.x * 256 + threadIdx.x) * 4;   // over [8192][256]
  int m = e >> 8, c = e & 255;
  short4 a = *(const short4*)(qa0 + (size_t)m * 384 + c);
  short4 b = *(const short4*)(qa1 + (size_t)m * 384 + c);
  float vx = bs2f(a.x) + bs2f(b.x);
  float vy = bs2f(a.y) + bs2f(b.y);
  float vz = bs2f(a.z) + bs2f(b.z);
  float vw = bs2f(a.w) + bs2f(b.w);
  short4 r;
  if (c < 128) {
    const float sc = 0.18033688011112042f;   // 0.125*log2e
    r.x = f2bs(vx * sc); r.y = f2bs(vy * sc);
    r.z = f2bs(vz * sc); r.w = f2bs(vw * sc);
    *(short4*)(qm + (size_t)m * 128 + c) = r;
  } else {
    r.x = f2bs(vx); r.y = f2bs(vy); r.z = f2bs(vz); r.w = f2bs(vw);
    *(short4*)(kb + (size_t)m * 128 + (c - 128)) = r;
  }
}

// ---- Kernel 2c: qa0+qa1 cols 256..383 -> vt[b][h][s'] via LDS transpose,
// with kv-permuted s' within each 32-block (lane-local P hand-off in attn):
//   dest low-5 = 8q+i  <-  source low-5 = (i<4) ? 4q+i : 16+4q+(i-4)
__global__ __launch_bounds__(256) void conv_v_kernel(const short* __restrict__ qa0,
                                                     const short* __restrict__ qa1,
                                                     short* __restrict__ vt) {
  const int tid = threadIdx.x;
  const int bb = blockIdx.x >> 6, st = blockIdx.x & 63;
  const int s0 = st * 64;

  __shared__ short ld[64][136];

  const int r = tid >> 2, c8 = (tid & 3) * 32;
#pragma unroll
  for (int q = 0; q < 4; ++q) {
    const size_t off = (size_t)(bb * 4096 + s0 + r) * 384 + 256 + c8 + q * 8;
    short8 a = *(const short8*)(qa0 + off);
    short8 b = *(const short8*)(qa1 + off);
    short8 o;
#pragma unroll
    for (int i = 0; i < 8; ++i) o[i] = f2bs(bs2f(a[i]) + bs2f(b[i]));
    *(short8*)(&ld[r][c8 + q * 8]) = o;
  }
  __syncthreads();

  const int h = tid >> 1, sh = (tid & 1) * 32;
#pragma unroll
  for (int q = 0; q < 4; ++q) {
    short8 t;
#pragma unroll
    for (int i = 0; i < 8; ++i) {
      int src5 = (i < 4) ? (4 * q + i) : (16 + 4 * q + (i - 4));
      t[i] = ld[sh + src5][h];
    }
    *(short8*)(vt + ((size_t)bb * 128 + h) * 4096 + s0 + sh + q * 8) = t;
  }
}

// ---- Kernel 3: LDS-staged flash attention (unchanged from R23: lane-local
// P hand-off via kv-permuted V, raw v_exp_f32, grid 1024, (256,3))
__global__ __launch_bounds__(256, 3) void attn_kernel(const short* __restrict__ qm,
                                                      const short* __restrict__ kb,
                                                      const short* __restrict__ vt,
                                                      short* __restrict__ po,
                                                      float* __restrict__ pls) {
  const int tid = threadIdx.x;
  const int w = tid >> 6;
  const int lane = tid & 63;
  const int lo = lane & 15, g = lane >> 4;
  const int qsp = w >> 1;
  const int s = w & 1;
  const int id = blockIdx.x;
  const int ksp = id & 7;
  const int qblk = id >> 3;
  const int b = qblk >> 6;
  const int kv_base = ksp * 512;

  __shared__ short kt[2][32 * 128];
  __shared__ short vl[2][128 * 32];

  const int kr0 = tid >> 4, kck = tid & 15;
  const int vr0 = tid >> 2, vck = tid & 3;
  const short* kS = kb + (size_t)b * S_LEN * HEADD;
  const short* vS = vt + (size_t)b * HEADD * S_LEN;
  const int kld0 = kr0 * 128 + ((kck ^ (kr0 & 7)) * 8);
  const int kld1 = (kr0 + 16) * 128 + ((kck ^ (kr0 & 7)) * 8);
  const int vld0 = vr0 * 32 + ((vck ^ (vr0 & 3)) * 8);
  const int vld1 = (vr0 + 64) * 32 + ((vck ^ (vr0 & 3)) * 8);

  const int rowqA = qblk * 64 + qsp * 32;
  const int rowqB = rowqA + 16;
  const short* qrowA = qm + (size_t)(rowqA + lo) * HEADD + s * 64;
  const short* qrowB = qm + (size_t)(rowqB + lo) * HEADD + s * 64;
  const short8 qA0 = *(const short8*)(qrowA + g * 8);
  const short8 qA1 = *(const short8*)(qrowA + 32 + g * 8);
  const short8 qB0 = *(const short8*)(qrowB + g * 8);
  const short8 qB1 = *(const short8*)(qrowB + 32 + g * 8);

  floatx4 accA[8], accB[8];
#pragma unroll
  for (int n = 0; n < 8; ++n) {
    accA[n] = floatx4{0.f, 0.f, 0.f, 0.f};
    accB[n] = floatx4{0.f, 0.f, 0.f, 0.f};
  }
  float lxA = 0.f, lxB = 0.f;

  const int kc0 = ((s * 8 + g) ^ (lo & 7)) * 8;
  const int kc1 = ((s * 8 + 4 + g) ^ (lo & 7)) * 8;
  const int kro0 = lo * 128, kro1 = (16 + lo) * 128;
  const int vco = (g ^ (lo & 3)) * 8;

  {
    int4 ka = *(const int4*)(kS + (size_t)(kv_base + kr0) * HEADD + kck * 8);
    int4 kbx = *(const int4*)(kS + (size_t)(kv_base + kr0 + 16) * HEADD + kck * 8);
    int4 va = *(const int4*)(vS + (size_t)vr0 * S_LEN + kv_base + vck * 8);
    int4 vb = *(const int4*)(vS + (size_t)(vr0 + 64) * S_LEN + kv_base + vck * 8);
    *(int4*)(&kt[0][kld0]) = ka;
    *(int4*)(&kt[0][kld1]) = kbx;
    *(int4*)(&vl[0][vld0]) = va;
    *(int4*)(&vl[0][vld1]) = vb;
  }
  __syncthreads();

  int cur = 0;
#pragma unroll 1
  for (int it = 0; it < 16; ++it) {
    int4 ka, kbx, va, vb;
    if (it + 1 < 16) {
      const int kvn = kv_base + (it + 1) * 32;
      ka  = *(const int4*)(kS + (size_t)(kvn + kr0) * HEADD + kck * 8);
      kbx = *(const int4*)(kS + (size_t)(kvn + kr0 + 16) * HEADD + kck * 8);
      va  = *(const int4*)(vS + (size_t)vr0 * S_LEN + kvn + vck * 8);
      vb  = *(const int4*)(vS + (size_t)(vr0 + 64) * S_LEN + kvn + vck * 8);
    }

    const short* kbase = &kt[cur][0];
    short8 a00 = *(const short8*)(kbase + kro0 + kc0);
    short8 a01 = *(const short8*)(kbase + kro0 + kc1);
    short8 a10 = *(const short8*)(kbase + kro1 + kc0);
    short8 a11 = *(const short8*)(kbase + kro1 + kc1);

    floatx4 z = floatx4{0.f, 0.f, 0.f, 0.f};
    floatx4 u;
    u = __builtin_amdgcn_mfma_f32_16x16x32_bf16(a00, qA0, z, 0, 0, 0);
    floatx4 T0A = __builtin_amdgcn_mfma_f32_16x16x32_bf16(a01, qA1, u, 0, 0, 0);
    u = __builtin_amdgcn_mfma_f32_16x16x32_bf16(a10, qA0, z, 0, 0, 0);
    floatx4 T1A = __builtin_amdgcn_mfma_f32_16x16x32_bf16(a11, qA1, u, 0, 0, 0);
    u = __builtin_amdgcn_mfma_f32_16x16x32_bf16(a00, qB0, z, 0, 0, 0);
    floatx4 T0B = __builtin_amdgcn_mfma_f32_16x16x32_bf16(a01, qB1, u, 0, 0, 0);
    u = __builtin_amdgcn_mfma_f32_16x16x32_bf16(a10, qB0, z, 0, 0, 0);
    floatx4 T1B = __builtin_amdgcn_mfma_f32_16x16x32_bf16(a11, qB1, u, 0, 0, 0);

    short8 paA, paB;
    {
      float p0 = fexp2(T0A[0]), p1 = fexp2(T0A[1]), p2 = fexp2(T0A[2]), p3 = fexp2(T0A[3]);
      float p4 = fexp2(T1A[0]), p5 = fexp2(T1A[1]), p6 = fexp2(T1A[2]), p7 = fexp2(T1A[3]);
      float lp = ((p0 + p1) + (p2 + p3)) + ((p4 + p5) + (p6 + p7));
      lp += __shfl_xor(lp, 16);
      lp += __shfl_xor(lp, 32);
      lxA += lp;
      int4 tmp = {pkbf(p0, p1), pkbf(p2, p3), pkbf(p4, p5), pkbf(p6, p7)};
      __builtin_memcpy(&paA, &tmp, 16);
    }
    {
      float p0 = fexp2(T0B[0]), p1 = fexp2(T0B[1]), p2 = fexp2(T0B[2]), p3 = fexp2(T0B[3]);
      float p4 = fexp2(T1B[0]), p5 = fexp2(T1B[1]), p6 = fexp2(T1B[2]), p7 = fexp2(T1B[3]);
      float lp = ((p0 + p1) + (p2 + p3)) + ((p4 + p5) + (p6 + p7));
      lp += __shfl_xor(lp, 16);
      lp += __shfl_xor(lp, 32);
      lxB += lp;
      int4 tmp = {pkbf(p0, p1), pkbf(p2, p3), pkbf(p4, p5), pkbf(p6, p7)};
      __builtin_memcpy(&paB, &tmp, 16);
    }

    const short* vbase = &vl[cur][0];
#pragma unroll
    for (int n = 0; n < 8; ++n) {
      short8 vf = *(const short8*)(vbase + (n * 16 + lo) * 32 + vco);
      accA[n] = __builtin_amdgcn_mfma_f32_16x16x32_bf16(paA, vf, accA[n], 0, 0, 0);
      accB[n] = __builtin_amdgcn_mfma_f32_16x16x32_bf16(paB, vf, accB[n], 0, 0, 0);
    }

    if (it + 1 < 16) {
      *(int4*)(&kt[cur ^ 1][kld0]) = ka;
      *(int4*)(&kt[cur ^ 1][kld1]) = kbx;
      *(int4*)(&vl[cur ^ 1][vld0]) = va;
      *(int4*)(&vl[cur ^ 1][vld1]) = vb;
    }
    __syncthreads();
    cur ^= 1;
  }

  short* pw = po + ((size_t)(ksp * 2 + s) * 8192) * 128;
#pragma unroll
  for (int j = 0; j < 4; ++j) {
    short8 pk;
#pragma unroll
    for (int n = 0; n < 8; ++n) pk[n] = f2bs(accA[n][j]);
    *(short8*)(pw + (size_t)(rowqA + g * 4 + j) * 128 + lo * 8) = pk;
#pragma unroll
    for (int n = 0; n < 8; ++n) pk[n] = f2bs(accB[n][j]);
    *(short8*)(pw + (size_t)(rowqB + g * 4 + j) * 128 + lo * 8) = pk;
  }
  if (g == 0) {
    pls[(size_t)(ksp * 2 + s) * 8192 + rowqA + lo] = lxA;
    pls[(size_t)(ksp * 2 + s) * 8192 + rowqB + lo] = lxB;
  }
}

// ---- Kernel 4: merge 8 ksp partials + diff combine + RMSNorm -> out (unchanged)
__global__ __launch_bounds__(256) void merge_kernel(const short* __restrict__ po,
                                                    const float* __restrict__ pls,
                                                    const float* __restrict__ lq1,
                                                    const float* __restrict__ lq2,
                                                    const float* __restrict__ lk1,
                                                    const float* __restrict__ lk2,
                                                    const float* __restrict__ rmsw,
                                                    float* __restrict__ out) {
  const int tid = threadIdx.x;
  const int row = blockIdx.x * 16 + (tid >> 4);
  const int lo = tid & 15;

  float a1s = 0.f, a2s = 0.f;
  for (int i = 0; i < 64; ++i) {
    a1s = fmaf(lq1[i], lk1[i], a1s);
    a2s = fmaf(lq2[i], lk2[i], a2s);
  }
  const float lam = __expf(a1s) - __expf(a2s) + 0.7836057665316245f;

  float o1[8], o2[8];
#pragma unroll
  for (int n = 0; n < 8; ++n) { o1[n] = 0.f; o2[n] = 0.f; }
  float l1 = 0.f, l2 = 0.f;
#pragma unroll
  for (int ksp = 0; ksp < 8; ++ksp) {
    short8 sa = *(const short8*)(po + ((size_t)(ksp * 2 + 0) * 8192 + row) * 128 + lo * 8);
    short8 sb = *(const short8*)(po + ((size_t)(ksp * 2 + 1) * 8192 + row) * 128 + lo * 8);
#pragma unroll
    for (int n = 0; n < 8; ++n) { o1[n] += bs2f(sa[n]); o2[n] += bs2f(sb[n]); }
    l1 += pls[(size_t)(ksp * 2 + 0) * 8192 + row];
    l2 += pls[(size_t)(ksp * 2 + 1) * 8192 + row];
  }
  const float iL1 = 1.f / l1, iL2 = 1.f / l2;

  float v[8];
  float ssq = 0.f;
#pragma unroll
  for (int n = 0; n < 8; ++n) {
    v[n] = o1[n] * iL1 - lam * (o2[n] * iL2);
    ssq += v[n] * v[n];
  }
  ssq += __shfl_xor(ssq, 1);
  ssq += __shfl_xor(ssq, 2);
  ssq += __shfl_xor(ssq, 4);
  ssq += __shfl_xor(ssq, 8);
  const float rr = rsqrtf(ssq * (1.f / 128.f) + 1.1920928955078125e-07f);

  float* ob = out + (size_t)row * 128;
#pragma unroll
  for (int n = 0; n < 8; ++n) {
    int c = n * 16 + lo;
    ob[c] = 0.21639423346837554f * v[n] * rr * rmsw[c];
  }
}

extern "C" void kernel_launch(void* const* d_in, const int* in_sizes, int n_in,
                              void* d_out, int out_size, void* d_ws, size_t ws_size,
                              hipStream_t stream) {
  const float* x   = (const float*)d_in[0];
  const float* wq  = (const float*)d_in[1];
  const float* wk  = (const float*)d_in[2];
  const float* wv  = (const float*)d_in[3];
  const float* lq1 = (const float*)d_in[4];
  const float* lq2 = (const float*)d_in[5];
  const float* lk1 = (const float*)d_in[6];
  const float* lk2 = (const float*)d_in[7];
  const float* rw  = (const float*)d_in[8];
  float* out = (float*)d_out;

  char* ws = (char*)d_ws;
  short* qm  = (short*)(ws);                        // 2 MB (q pre-scaled 0.125*log2e)
  short* kb  = (short*)(ws + (2u << 20));           // 2 MB
  short* vt  = (short*)(ws + (4u << 20));           // 2 MB (V^T, kv-permuted per 32)
  short* wc  = (short*)(ws + (6u << 20));           // 1.5 MB
  short* qa0 = (short*)(ws + (8u << 20));           // 6.3 MB bf16 [8192][384] (kh=0)
  short* qa1 = (short*)(ws + (8u << 20) + 6291456u);// 6.3 MB (kh=1)
  short* po  = (short*)(ws + (8u << 20));           // 32 MB (aliases qa; qa dead by attn)
  float* pls = (float*)(ws + (40u << 20));          // 512 KB fp32 [16][8192]

  convw_kernel<<<768, 256, 0, stream>>>(wq, wk, wv, wc);
  proj_kernel<<<1024, 256, 0, stream>>>(x, wc, qa0, qa1);
  conv_qk_kernel<<<2048, 256, 0, stream>>>(qa0, qa1, qm, kb);
  conv_v_kernel<<<128, 256, 0, stream>>>(qa0, qa1, vt);
  attn_kernel<<<1024, 256, 0, stream>>>(qm, kb, vt, po, pls);
  merge_kernel<<<512, 256, 0, stream>>>(po, pls, lq1, lq2, lk1, lk2, rw, out);
}

// Round 25
// 90.430 us; speedup vs baseline: 1.1496x; 1.0181x over previous
//
#include <hip/hip_runtime.h>
#include <hip/hip_bf16.h>
#include <math.h>

#define S_LEN 4096
#define DMODEL 2048
#define HEADD 128

typedef __attribute__((ext_vector_type(8))) short short8;
typedef __attribute__((ext_vector_type(4))) float floatx4;

__device__ __forceinline__ short f2bs(float f) {
  __hip_bfloat16 h = __float2bfloat16(f);
  short s; __builtin_memcpy(&s, &h, 2); return s;
}
__device__ __forceinline__ float bs2f(short s) {
  unsigned u = ((unsigned)(unsigned short)s) << 16;
  float f; __builtin_memcpy(&f, &u, 4); return f;
}
__device__ __forceinline__ int pkbf(float a, float b) {  // (lo=a, hi=b) bf16 pair
  return (int)(((unsigned)(unsigned short)f2bs(b) << 16) |
               (unsigned)(unsigned short)f2bs(a));
}
// raw v_exp_f32: 2^x, no libm guard code (R21/R22 lesson)
__device__ __forceinline__ float fexp2(float x) { return __builtin_amdgcn_exp2f(x); }

// ---- Kernel 1: convert Wq,Wk,Wv (fp32 [128][2048] each) -> wc bf16 [384][2048]
__global__ __launch_bounds__(256) void convw_kernel(const float* __restrict__ wq,
                                                    const float* __restrict__ wk,
                                                    const float* __restrict__ wv,
                                                    short* __restrict__ wc) {
  const int per = 128 * 2048;
  int e = (blockIdx.x * blockDim.x + threadIdx.x) * 4;
  const float* src = (e < per) ? wq : (e < 2 * per) ? wk : wv;
  int off = e & (per - 1);
  float4 v = *(const float4*)(src + off);
  short4 r;
  r.x = f2bs(v.x); r.y = f2bs(v.y); r.z = f2bs(v.z); r.w = f2bs(v.w);
  *(short4*)(wc + e) = r;
}

// ---- Kernel 2: projection GEMM, dense 64x96 tile + kh-split.
// (256,4): LDS 40KB fits exactly 4 blocks/CU (160KB); grid 1024 = one clean
// round of 4/CU = 16 waves/CU (R24 ran 3 ragged). Reg headroom large.
__global__ __launch_bounds__(256, 4) void proj_kernel(const float* __restrict__ x,
                                                      const short* __restrict__ wc,
                                                      short* __restrict__ qa0,
                                                      short* __restrict__ qa1) {
  const int tid = threadIdx.x;
  const int w = tid >> 6;
  const int lane = tid & 63;
  const int lo = lane & 15, g = lane >> 4;
  const int id = blockIdx.x;
  const int kh = id >> 9, nq = (id >> 7) & 3, mb = id & 127;
  const int m0 = mb * 64;
  const int n0 = nq * 96;
  const int k0 = kh * 1024;
  short* qa = kh ? qa1 : qa0;

  __shared__ short xt[2][64 * 64];
  __shared__ short wt[2][96 * 64];

  const int r8 = tid >> 3, sc = tid & 7;
  const float* xs0 = x + (size_t)(m0 + r8) * DMODEL + k0 + sc * 8;
  const float* xs1 = x + (size_t)(m0 + 32 + r8) * DMODEL + k0 + sc * 8;
  const short* ws0 = wc + (size_t)(n0 + r8) * DMODEL + k0 + sc * 8;
  const short* ws1 = wc + (size_t)(n0 + 32 + r8) * DMODEL + k0 + sc * 8;
  const short* ws2 = wc + (size_t)(n0 + 64 + r8) * DMODEL + k0 + sc * 8;
  const int xl0 = r8 * 64 + ((sc ^ (r8 & 7)) * 8);
  const int xl1 = (32 + r8) * 64 + ((sc ^ (r8 & 7)) * 8);
  const int wlo0 = r8 * 64 + ((sc ^ (r8 & 7)) * 8);
  const int wlo1 = (32 + r8) * 64 + ((sc ^ (r8 & 7)) * 8);
  const int wlo2 = (64 + r8) * 64 + ((sc ^ (r8 & 7)) * 8);

  const int mrow = (w >> 1) * 32;
  const int ncol = (w & 1) * 48;
  int aoff[2][2], boff[3][2];
#pragma unroll
  for (int mi = 0; mi < 2; ++mi) {
    int r = mrow + mi * 16 + lo;
#pragma unroll
    for (int kc = 0; kc < 2; ++kc)
      aoff[mi][kc] = r * 64 + (((kc * 4 + g) ^ (r & 7)) * 8);
  }
#pragma unroll
  for (int t = 0; t < 3; ++t) {
    int r = ncol + t * 16 + lo;
#pragma unroll
    for (int kc = 0; kc < 2; ++kc)
      boff[t][kc] = r * 64 + (((kc * 4 + g) ^ (r & 7)) * 8);
  }

  floatx4 acc[2][3];
#pragma unroll
  for (int mi = 0; mi < 2; ++mi)
#pragma unroll
    for (int t = 0; t < 3; ++t) acc[mi][t] = floatx4{0.f, 0.f, 0.f, 0.f};

  {
    float4 a0 = *(const float4*)(xs0), a1 = *(const float4*)(xs0 + 4);
    float4 b0 = *(const float4*)(xs1), b1 = *(const float4*)(xs1 + 4);
    int4 w0 = *(const int4*)(ws0);
    int4 w1 = *(const int4*)(ws1);
    int4 w2 = *(const int4*)(ws2);
    short8 sA, sB;
    sA[0]=f2bs(a0.x); sA[1]=f2bs(a0.y); sA[2]=f2bs(a0.z); sA[3]=f2bs(a0.w);
    sA[4]=f2bs(a1.x); sA[5]=f2bs(a1.y); sA[6]=f2bs(a1.z); sA[7]=f2bs(a1.w);
    sB[0]=f2bs(b0.x); sB[1]=f2bs(b0.y); sB[2]=f2bs(b0.z); sB[3]=f2bs(b0.w);
    sB[4]=f2bs(b1.x); sB[5]=f2bs(b1.y); sB[6]=f2bs(b1.z); sB[7]=f2bs(b1.w);
    *(short8*)&xt[0][xl0] = sA;
    *(short8*)&xt[0][xl1] = sB;
    *(int4*)&wt[0][wlo0] = w0;
    *(int4*)&wt[0][wlo1] = w1;
    *(int4*)&wt[0][wlo2] = w2;
  }
  __syncthreads();

  int cur = 0;
#pragma unroll 1
  for (int it = 0; it < 16; ++it) {
    float4 a0, a1, b0, b1;
    int4 w0, w1, w2;
    if (it + 1 < 16) {
      const int k = (it + 1) * 64;
      a0 = *(const float4*)(xs0 + k); a1 = *(const float4*)(xs0 + k + 4);
      b0 = *(const float4*)(xs1 + k); b1 = *(const float4*)(xs1 + k + 4);
      w0 = *(const int4*)(ws0 + k);
      w1 = *(const int4*)(ws1 + k);
      w2 = *(const int4*)(ws2 + k);
    }

    {
      const short* xb = &xt[cur][0];
      const short* wb = &wt[cur][0];
      short8 af[2][2], bf[3][2];
#pragma unroll
      for (int mi = 0; mi < 2; ++mi)
#pragma unroll
        for (int kc = 0; kc < 2; ++kc) af[mi][kc] = *(const short8*)(xb + aoff[mi][kc]);
#pragma unroll
      for (int t = 0; t < 3; ++t)
#pragma unroll
        for (int kc = 0; kc < 2; ++kc) bf[t][kc] = *(const short8*)(wb + boff[t][kc]);
#pragma unroll
      for (int kc = 0; kc < 2; ++kc)
#pragma unroll
        for (int mi = 0; mi < 2; ++mi)
#pragma unroll
          for (int t = 0; t < 3; ++t)
            acc[mi][t] = __builtin_amdgcn_mfma_f32_16x16x32_bf16(af[mi][kc], bf[t][kc], acc[mi][t], 0, 0, 0);
    }

    if (it + 1 < 16) {
      short8 sA, sB;
      sA[0]=f2bs(a0.x); sA[1]=f2bs(a0.y); sA[2]=f2bs(a0.z); sA[3]=f2bs(a0.w);
      sA[4]=f2bs(a1.x); sA[5]=f2bs(a1.y); sA[6]=f2bs(a1.z); sA[7]=f2bs(a1.w);
      sB[0]=f2bs(b0.x); sB[1]=f2bs(b0.y); sB[2]=f2bs(b0.z); sB[3]=f2bs(b0.w);
      sB[4]=f2bs(b1.x); sB[5]=f2bs(b1.y); sB[6]=f2bs(b1.z); sB[7]=f2bs(b1.w);
      *(short8*)&xt[cur ^ 1][xl0] = sA;
      *(short8*)&xt[cur ^ 1][xl1] = sB;
      *(int4*)&wt[cur ^ 1][wlo0] = w0;
      *(int4*)&wt[cur ^ 1][wlo1] = w1;
      *(int4*)&wt[cur ^ 1][wlo2] = w2;
    }
    __syncthreads();
    cur ^= 1;
  }

#pragma unroll
  for (int t = 0; t < 3; ++t) {
    int n = n0 + ncol + t * 16 + lo;
#pragma unroll
    for (int mi = 0; mi < 2; ++mi)
#pragma unroll
      for (int j = 0; j < 4; ++j) {
        int m = m0 + mrow + mi * 16 + g * 4 + j;
        qa[(size_t)m * 384 + n] = f2bs(acc[mi][t][j]);
      }
  }
}

// ---- Kernel 2b: qa0+qa1 cols 0..255 -> qm (scaled 0.125*log2e), kb
__global__ __launch_bounds__(256) void conv_qk_kernel(const short* __restrict__ qa0,
                                                      const short* __restrict__ qa1,
                                                      short* __restrict__ qm,
                                                      short* __restrict__ kb) {
  int e = (blockIdx.x * 256 + threadIdx.x) * 4;   // over [8192][256]
  int m = e >> 8, c = e & 255;
  short4 a = *(const short4*)(qa0 + (size_t)m * 384 + c);
  short4 b = *(const short4*)(qa1 + (size_t)m * 384 + c);
  float vx = bs2f(a.x) + bs2f(b.x);
  float vy = bs2f(a.y) + bs2f(b.y);
  float vz = bs2f(a.z) + bs2f(b.z);
  float vw = bs2f(a.w) + bs2f(b.w);
  short4 r;
  if (c < 128) {
    const float sc = 0.18033688011112042f;   // 0.125*log2e
    r.x = f2bs(vx * sc); r.y = f2bs(vy * sc);
    r.z = f2bs(vz * sc); r.w = f2bs(vw * sc);
    *(short4*)(qm + (size_t)m * 128 + c) = r;
  } else {
    r.x = f2bs(vx); r.y = f2bs(vy); r.z = f2bs(vz); r.w = f2bs(vw);
    *(short4*)(kb + (size_t)m * 128 + (c - 128)) = r;
  }
}

// ---- Kernel 2c: qa0+qa1 cols 256..383 -> vt[b][h][s'] via LDS transpose,
// kv-permuted s' within each 32-block (lane-local P hand-off in attn)
__global__ __launch_bounds__(256) void conv_v_kernel(const short* __restrict__ qa0,
                                                     const short* __restrict__ qa1,
                                                     short* __restrict__ vt) {
  const int tid = threadIdx.x;
  const int bb = blockIdx.x >> 6, st = blockIdx.x & 63;
  const int s0 = st * 64;

  __shared__ short ld[64][136];

  const int r = tid >> 2, c8 = (tid & 3) * 32;
#pragma unroll
  for (int q = 0; q < 4; ++q) {
    const size_t off = (size_t)(bb * 4096 + s0 + r) * 384 + 256 + c8 + q * 8;
    short8 a = *(const short8*)(qa0 + off);
    short8 b = *(const short8*)(qa1 + off);
    short8 o;
#pragma unroll
    for (int i = 0; i < 8; ++i) o[i] = f2bs(bs2f(a[i]) + bs2f(b[i]));
    *(short8*)(&ld[r][c8 + q * 8]) = o;
  }
  __syncthreads();

  const int h = tid >> 1, sh = (tid & 1) * 32;
#pragma unroll
  for (int q = 0; q < 4; ++q) {
    short8 t;
#pragma unroll
    for (int i = 0; i < 8; ++i) {
      int src5 = (i < 4) ? (4 * q + i) : (16 + 4 * q + (i - 4));
      t[i] = ld[sh + src5][h];
    }
    *(short8*)(vt + ((size_t)bb * 128 + h) * 4096 + s0 + sh + q * 8) = t;
  }
}

// ---- Kernel 3: LDS-staged flash attention. NEW: l via ones-column MFMA
// (matrix pipe has headroom at 22%) -- deletes 12 fadds + 4 shfl_xor
// (LDS-pipe ops) per wave-iter. l lands in lanes lo==0, reg j <-> row g*4+j.
__global__ __launch_bounds__(256, 3) void attn_kernel(const short* __restrict__ qm,
                                                      const short* __restrict__ kb,
                                                      const short* __restrict__ vt,
                                                      short* __restrict__ po,
                                                      float* __restrict__ pls) {
  const int tid = threadIdx.x;
  const int w = tid >> 6;
  const int lane = tid & 63;
  const int lo = lane & 15, g = lane >> 4;
  const int qsp = w >> 1;
  const int s = w & 1;
  const int id = blockIdx.x;
  const int ksp = id & 7;
  const int qblk = id >> 3;
  const int b = qblk >> 6;
  const int kv_base = ksp * 512;

  __shared__ short kt[2][32 * 128];
  __shared__ short vl[2][128 * 32];

  const int kr0 = tid >> 4, kck = tid & 15;
  const int vr0 = tid >> 2, vck = tid & 3;
  const short* kS = kb + (size_t)b * S_LEN * HEADD;
  const short* vS = vt + (size_t)b * HEADD * S_LEN;
  const int kld0 = kr0 * 128 + ((kck ^ (kr0 & 7)) * 8);
  const int kld1 = (kr0 + 16) * 128 + ((kck ^ (kr0 & 7)) * 8);
  const int vld0 = vr0 * 32 + ((vck ^ (vr0 & 3)) * 8);
  const int vld1 = (vr0 + 64) * 32 + ((vck ^ (vr0 & 3)) * 8);

  const int rowqA = qblk * 64 + qsp * 32;
  const int rowqB = rowqA + 16;
  const short* qrowA = qm + (size_t)(rowqA + lo) * HEADD + s * 64;
  const short* qrowB = qm + (size_t)(rowqB + lo) * HEADD + s * 64;
  const short8 qA0 = *(const short8*)(qrowA + g * 8);
  const short8 qA1 = *(const short8*)(qrowA + 32 + g * 8);
  const short8 qB0 = *(const short8*)(qrowB + g * 8);
  const short8 qB1 = *(const short8*)(qrowB + 32 + g * 8);

  floatx4 accA[8], accB[8];
#pragma unroll
  for (int n = 0; n < 8; ++n) {
    accA[n] = floatx4{0.f, 0.f, 0.f, 0.f};
    accB[n] = floatx4{0.f, 0.f, 0.f, 0.f};
  }
  floatx4 lxA = floatx4{0.f, 0.f, 0.f, 0.f};
  floatx4 lxB = floatx4{0.f, 0.f, 0.f, 0.f};

  // ones-column B-frag: B[k][0]=1 for all k -> lanes lo==0 hold 1.0 in all slots
  short8 onesb;
  {
    short one = (short)0x3F80;
#pragma unroll
    for (int jj = 0; jj < 8; ++jj) onesb[jj] = (lo == 0) ? one : (short)0;
  }

  const int kc0 = ((s * 8 + g) ^ (lo & 7)) * 8;
  const int kc1 = ((s * 8 + 4 + g) ^ (lo & 7)) * 8;
  const int kro0 = lo * 128, kro1 = (16 + lo) * 128;
  const int vco = (g ^ (lo & 3)) * 8;

  {
    int4 ka = *(const int4*)(kS + (size_t)(kv_base + kr0) * HEADD + kck * 8);
    int4 kbx = *(const int4*)(kS + (size_t)(kv_base + kr0 + 16) * HEADD + kck * 8);
    int4 va = *(const int4*)(vS + (size_t)vr0 * S_LEN + kv_base + vck * 8);
    int4 vb = *(const int4*)(vS + (size_t)(vr0 + 64) * S_LEN + kv_base + vck * 8);
    *(int4*)(&kt[0][kld0]) = ka;
    *(int4*)(&kt[0][kld1]) = kbx;
    *(int4*)(&vl[0][vld0]) = va;
    *(int4*)(&vl[0][vld1]) = vb;
  }
  __syncthreads();

  int cur = 0;
#pragma unroll 1
  for (int it = 0; it < 16; ++it) {
    int4 ka, kbx, va, vb;
    if (it + 1 < 16) {
      const int kvn = kv_base + (it + 1) * 32;
      ka  = *(const int4*)(kS + (size_t)(kvn + kr0) * HEADD + kck * 8);
      kbx = *(const int4*)(kS + (size_t)(kvn + kr0 + 16) * HEADD + kck * 8);
      va  = *(const int4*)(vS + (size_t)vr0 * S_LEN + kvn + vck * 8);
      vb  = *(const int4*)(vS + (size_t)(vr0 + 64) * S_LEN + kvn + vck * 8);
    }

    const short* kbase = &kt[cur][0];
    short8 a00 = *(const short8*)(kbase + kro0 + kc0);
    short8 a01 = *(const short8*)(kbase + kro0 + kc1);
    short8 a10 = *(const short8*)(kbase + kro1 + kc0);
    short8 a11 = *(const short8*)(kbase + kro1 + kc1);

    floatx4 z = floatx4{0.f, 0.f, 0.f, 0.f};
    floatx4 u;
    u = __builtin_amdgcn_mfma_f32_16x16x32_bf16(a00, qA0, z, 0, 0, 0);
    floatx4 T0A = __builtin_amdgcn_mfma_f32_16x16x32_bf16(a01, qA1, u, 0, 0, 0);
    u = __builtin_amdgcn_mfma_f32_16x16x32_bf16(a10, qA0, z, 0, 0, 0);
    floatx4 T1A = __builtin_amdgcn_mfma_f32_16x16x32_bf16(a11, qA1, u, 0, 0, 0);
    u = __builtin_amdgcn_mfma_f32_16x16x32_bf16(a00, qB0, z, 0, 0, 0);
    floatx4 T0B = __builtin_amdgcn_mfma_f32_16x16x32_bf16(a01, qB1, u, 0, 0, 0);
    u = __builtin_amdgcn_mfma_f32_16x16x32_bf16(a10, qB0, z, 0, 0, 0);
    floatx4 T1B = __builtin_amdgcn_mfma_f32_16x16x32_bf16(a11, qB1, u, 0, 0, 0);

    short8 paA, paB;
    {
      float p0 = fexp2(T0A[0]), p1 = fexp2(T0A[1]), p2 = fexp2(T0A[2]), p3 = fexp2(T0A[3]);
      float p4 = fexp2(T1A[0]), p5 = fexp2(T1A[1]), p6 = fexp2(T1A[2]), p7 = fexp2(T1A[3]);
      int4 tmp = {pkbf(p0, p1), pkbf(p2, p3), pkbf(p4, p5), pkbf(p6, p7)};
      __builtin_memcpy(&paA, &tmp, 16);
    }
    {
      float p0 = fexp2(T0B[0]), p1 = fexp2(T0B[1]), p2 = fexp2(T0B[2]), p3 = fexp2(T0B[3]);
      float p4 = fexp2(T1B[0]), p5 = fexp2(T1B[1]), p6 = fexp2(T1B[2]), p7 = fexp2(T1B[3]);
      int4 tmp = {pkbf(p0, p1), pkbf(p2, p3), pkbf(p4, p5), pkbf(p6, p7)};
      __builtin_memcpy(&paB, &tmp, 16);
    }

    const short* vbase = &vl[cur][0];
#pragma unroll
    for (int n = 0; n < 8; ++n) {
      short8 vf = *(const short8*)(vbase + (n * 16 + lo) * 32 + vco);
      accA[n] = __builtin_amdgcn_mfma_f32_16x16x32_bf16(paA, vf, accA[n], 0, 0, 0);
      accB[n] = __builtin_amdgcn_mfma_f32_16x16x32_bf16(paB, vf, accB[n], 0, 0, 0);
    }
    // l row-sums on the matrix pipe (replaces fadd chain + shfl_xor)
    lxA = __builtin_amdgcn_mfma_f32_16x16x32_bf16(paA, onesb, lxA, 0, 0, 0);
    lxB = __builtin_amdgcn_mfma_f32_16x16x32_bf16(paB, onesb, lxB, 0, 0, 0);

    if (it + 1 < 16) {
      *(int4*)(&kt[cur ^ 1][kld0]) = ka;
      *(int4*)(&kt[cur ^ 1][kld1]) = kbx;
      *(int4*)(&vl[cur ^ 1][vld0]) = va;
      *(int4*)(&vl[cur ^ 1][vld1]) = vb;
    }
    __syncthreads();
    cur ^= 1;
  }

  short* pw = po + ((size_t)(ksp * 2 + s) * 8192) * 128;
#pragma unroll
  for (int j = 0; j < 4; ++j) {
    short8 pk;
#pragma unroll
    for (int n = 0; n < 8; ++n) pk[n] = f2bs(accA[n][j]);
    *(short8*)(pw + (size_t)(rowqA + g * 4 + j) * 128 + lo * 8) = pk;
#pragma unroll
    for (int n = 0; n < 8; ++n) pk[n] = f2bs(accB[n][j]);
    *(short8*)(pw + (size_t)(rowqB + g * 4 + j) * 128 + lo * 8) = pk;
  }
  // l: D[row=g*4+j][col=lo], ones column -> col 0 = lanes lo==0
  if (lo == 0) {
#pragma unroll
    for (int j = 0; j < 4; ++j) {
      pls[(size_t)(ksp * 2 + s) * 8192 + rowqA + g * 4 + j] = lxA[j];
      pls[(size_t)(ksp * 2 + s) * 8192 + rowqB + g * 4 + j] = lxB[j];
    }
  }
}

// ---- Kernel 4: merge 8 ksp partials + diff combine + RMSNorm -> out (unchanged)
__global__ __launch_bounds__(256) void merge_kernel(const short* __restrict__ po,
                                                    const float* __restrict__ pls,
                                                    const float* __restrict__ lq1,
                                                    const float* __restrict__ lq2,
                                                    const float* __restrict__ lk1,
                                                    const float* __restrict__ lk2,
                                                    const float* __restrict__ rmsw,
                                                    float* __restrict__ out) {
  const int tid = threadIdx.x;
  const int row = blockIdx.x * 16 + (tid >> 4);
  const int lo = tid & 15;

  float a1s = 0.f, a2s = 0.f;
  for (int i = 0; i < 64; ++i) {
    a1s = fmaf(lq1[i], lk1[i], a1s);
    a2s = fmaf(lq2[i], lk2[i], a2s);
  }
  const float lam = __expf(a1s) - __expf(a2s) + 0.7836057665316245f;

  float o1[8], o2[8];
#pragma unroll
  for (int n = 0; n < 8; ++n) { o1[n] = 0.f; o2[n] = 0.f; }
  float l1 = 0.f, l2 = 0.f;
#pragma unroll
  for (int ksp = 0; ksp < 8; ++ksp) {
    short8 sa = *(const short8*)(po + ((size_t)(ksp * 2 + 0) * 8192 + row) * 128 + lo * 8);
    short8 sb = *(const short8*)(po + ((size_t)(ksp * 2 + 1) * 8192 + row) * 128 + lo * 8);
#pragma unroll
    for (int n = 0; n < 8; ++n) { o1[n] += bs2f(sa[n]); o2[n] += bs2f(sb[n]); }
    l1 += pls[(size_t)(ksp * 2 + 0) * 8192 + row];
    l2 += pls[(size_t)(ksp * 2 + 1) * 8192 + row];
  }
  const float iL1 = 1.f / l1, iL2 = 1.f / l2;

  float v[8];
  float ssq = 0.f;
#pragma unroll
  for (int n = 0; n < 8; ++n) {
    v[n] = o1[n] * iL1 - lam * (o2[n] * iL2);
    ssq += v[n] * v[n];
  }
  ssq += __shfl_xor(ssq, 1);
  ssq += __shfl_xor(ssq, 2);
  ssq += __shfl_xor(ssq, 4);
  ssq += __shfl_xor(ssq, 8);
  const float rr = rsqrtf(ssq * (1.f / 128.f) + 1.1920928955078125e-07f);

  float* ob = out + (size_t)row * 128;
#pragma unroll
  for (int n = 0; n < 8; ++n) {
    int c = n * 16 + lo;
    ob[c] = 0.21639423346837554f * v[n] * rr * rmsw[c];
  }
}

extern "C" void kernel_launch(void* const* d_in, const int* in_sizes, int n_in,
                              void* d_out, int out_size, void* d_ws, size_t ws_size,
                              hipStream_t stream) {
  const float* x   = (const float*)d_in[0];
  const float* wq  = (const float*)d_in[1];
  const float* wk  = (const float*)d_in[2];
  const float* wv  = (const float*)d_in[3];
  const float* lq1 = (const float*)d_in[4];
  const float* lq2 = (const float*)d_in[5];
  const float* lk1 = (const float*)d_in[6];
  const float* lk2 = (const float*)d_in[7];
  const float* rw  = (const float*)d_in[8];
  float* out = (float*)d_out;

  char* ws = (char*)d_ws;
  short* qm  = (short*)(ws);                        // 2 MB (q pre-scaled 0.125*log2e)
  short* kb  = (short*)(ws + (2u << 20));           // 2 MB
  short* vt  = (short*)(ws + (4u << 20));           // 2 MB (V^T, kv-permuted per 32)
  short* wc  = (short*)(ws + (6u << 20));           // 1.5 MB
  short* qa0 = (short*)(ws + (8u << 20));           // 6.3 MB bf16 [8192][384] (kh=0)
  short* qa1 = (short*)(ws + (8u << 20) + 6291456u);// 6.3 MB (kh=1)
  short* po  = (short*)(ws + (8u << 20));           // 32 MB (aliases qa; qa dead by attn)
  float* pls = (float*)(ws + (40u << 20));          // 512 KB fp32 [16][8192]

  convw_kernel<<<768, 256, 0, stream>>>(wq, wk, wv, wc);
  proj_kernel<<<1024, 256, 0, stream>>>(x, wc, qa0, qa1);
  conv_qk_kernel<<<2048, 256, 0, stream>>>(qa0, qa1, qm, kb);
  conv_v_kernel<<<128, 256, 0, stream>>>(qa0, qa1, vt);
  attn_kernel<<<1024, 256, 0, stream>>>(qm, kb, vt, po, pls);
  merge_kernel<<<512, 256, 0, stream>>>(po, pls, lq1, lq2, lk1, lk2, rw, out);
}